// Round 8
// baseline (451.971 us; speedup 1.0000x reference)
//
#include <hip/hip_runtime.h>
#include <stdint.h>

// ---------------------------------------------------------------------------
// TimeCondAttention on MI355X (gfx950)
// R8: ABLATION ROUND. k_attn_t<V>:
//   V3 = bias stream, deep MLP (16 loads in flight), no barriers  [REP=5]
//   V2 = bias stream, V0's ping-pong + barrier cadence            [REP=5]
//   V1 = full attention compute, bias forced to zero              [REP=6]
//   V0 = real kernel (identical to R7), writes po/ml              [REP=1]
// V3/V2/V1 write only scratch; V0 runs last -> output unchanged.
// ---------------------------------------------------------------------------

using s16x8 = __attribute__((ext_vector_type(8))) short;
using f32x4 = __attribute__((ext_vector_type(4))) float;
using u16x4 = __attribute__((ext_vector_type(4))) unsigned short;

#define EPSV 1e-5f
#define NEGV 1e6f

__device__ __forceinline__ unsigned short f2bf(float f) {
    unsigned int u = __float_as_uint(f);
    u += 0x7FFFu + ((u >> 16) & 1u);   // RNE (inputs finite)
    return (unsigned short)(u >> 16);
}
__device__ __forceinline__ float bf2f(unsigned short s) {
    return __uint_as_float((unsigned int)s << 16);
}

__device__ __forceinline__ void gl_lds16(const void* g, void* l) {
    __builtin_amdgcn_global_load_lds((const __attribute__((address_space(1))) void*)g,
                                     (__attribute__((address_space(3))) void*)l, 16, 0, 0);
}

__device__ __forceinline__ f32x4 mfma_bf16(s16x8 a, s16x8 b, f32x4 c) {
    return __builtin_amdgcn_mfma_f32_16x16x32_bf16(a, b, c, 0, 0, 0);
}

// ---------------- K0: weight conversion (w_q, w_kv bf16; w_out hi/lo split) --
__global__ void k_prep(const float* __restrict__ w_q, const float* __restrict__ w_kv,
                       const float* __restrict__ w_out,
                       unsigned short* __restrict__ wq, unsigned short* __restrict__ wkv,
                       unsigned short* __restrict__ wo_h, unsigned short* __restrict__ wo_l) {
    int idx = blockIdx.x * 256 + threadIdx.x;         // total 1,048,576 exactly
    if (idx < 262144) {
        wq[idx] = f2bf(w_q[idx]);
    } else if (idx < 786432) {
        int i = idx - 262144;
        wkv[i] = f2bf(w_kv[i]);
    } else {
        int i = idx - 786432;
        float v = w_out[i];
        unsigned short h = f2bf(v);
        wo_h[i] = h;
        wo_l[i] = f2bf(v - bf2f(h));
    }
}

// ---------------- K1: t = silu(time) @ w_time.T + b_time  ([2][1024] f32) ----
__global__ void k_time(const float* __restrict__ timev, const float* __restrict__ w_time,
                       const float* __restrict__ b_time, float* __restrict__ tc) {
    int wid = threadIdx.x >> 6, lane = threadIdx.x & 63;
    int b = blockIdx.x >> 8;
    int j = (blockIdx.x & 255) * 4 + wid;             // 0..1023
    const float* tv = timev + b * 512;
    const float* wr = w_time + (size_t)j * 512;
    float acc = 0.f;
#pragma unroll
    for (int i = 0; i < 8; ++i) {
        int k = i * 64 + lane;
        float t = tv[k];
        float s = t / (1.f + __expf(-t));             // silu
        acc += s * wr[k];
    }
#pragma unroll
    for (int m = 32; m >= 1; m >>= 1) acc += __shfl_xor(acc, m);
    if (lane == 0) tc[b * 1024 + j] = acc + b_time[j];
}

// ---------------- K2: LayerNorm + FiLM + seq_mask -> xn(bf16); x -> bf16 -----
__global__ void k_lnfilm(const float* __restrict__ x, const float* __restrict__ gamma,
                         const float* __restrict__ seq_mask, const float* __restrict__ tc,
                         unsigned short* __restrict__ xbf, unsigned short* __restrict__ xnbf) {
    int row = blockIdx.x;                             // b*2048 + n
    int b = row >> 11;
    int tid = threadIdx.x, wid = tid >> 6, lane = tid & 63;
    float2 xv = *(const float2*)(x + (size_t)row * 512 + tid * 2);
    float s = xv.x + xv.y;
    float sq = xv.x * xv.x + xv.y * xv.y;
#pragma unroll
    for (int m = 32; m >= 1; m >>= 1) { s += __shfl_xor(s, m); sq += __shfl_xor(sq, m); }
    __shared__ float red[8];
    if (lane == 0) { red[wid] = s; red[wid + 4] = sq; }
    __syncthreads();
    float ts = red[0] + red[1] + red[2] + red[3];
    float tq = red[4] + red[5] + red[6] + red[7];
    float mu = ts * (1.f / 512.f);
    float var = tq * (1.f / 512.f) - mu * mu;
    float rs = rsqrtf(var + EPSV);
    float qm = seq_mask[row];
    int j = tid * 2;
    const float* scb = tc + b * 1024;
    float o0 = ((xv.x - mu) * rs * gamma[j])     * (scb[j] + 1.f)     + scb[j + 512];
    float o1 = ((xv.y - mu) * rs * gamma[j + 1]) * (scb[j + 1] + 1.f) + scb[j + 513];
    size_t base = (size_t)row * 512 + j;
    xnbf[base]     = f2bf(o0 * qm);
    xnbf[base + 1] = f2bf(o1 * qm);
    xbf[base]      = f2bf(xv.x);
    xbf[base + 1]  = f2bf(xv.y);
}

// ---------------- K3: bf16 GEMM C = A[M,512] * W[Nout,512]^T, scatter epi ----
template<int EPI>
__launch_bounds__(256)
__global__ void k_gemm(const unsigned short* __restrict__ A, const unsigned short* __restrict__ W,
                       unsigned short* __restrict__ o0, unsigned short* __restrict__ o1) {
    __shared__ unsigned short a_t[128 * 64];
    __shared__ unsigned short b_t[128 * 64];
    int tid = threadIdx.x, lane = tid & 63, wid = tid >> 6;
    int lc = lane & 15, lq = lane >> 4;
    int wr = wid >> 1, wc = wid & 1;
    int m0 = blockIdx.x * 128, n0 = blockIdx.y * 128;
    f32x4 acc[4][4];
#pragma unroll
    for (int i = 0; i < 4; ++i)
#pragma unroll
        for (int jn = 0; jn < 4; ++jn)
#pragma unroll
            for (int e = 0; e < 4; ++e) acc[i][jn][e] = 0.f;
    const unsigned short* Ab = A + (size_t)m0 * 512;
    const unsigned short* Wb = W + (size_t)n0 * 512;
    int wbase = wid * 64;
    for (int kt = 0; kt < 8; ++kt) {
        __syncthreads();
#pragma unroll
        for (int i = 0; i < 4; ++i) {
            int p = i * 256 + wbase + lane;
            int row = p >> 3, ls = (p & 7) ^ (row & 7);
            gl_lds16(Ab + (size_t)row * 512 + kt * 64 + ls * 8, a_t + (i * 256 + wbase) * 8);
            gl_lds16(Wb + (size_t)row * 512 + kt * 64 + ls * 8, b_t + (i * 256 + wbase) * 8);
        }
        __syncthreads();
        s16x8 af[4][2], bw[4][2];
        const char* ab = (const char*)a_t;
        const char* bb = (const char*)b_t;
#pragma unroll
        for (int mf = 0; mf < 4; ++mf) {
            int row = wr * 64 + mf * 16 + lc;
            int key = (row & 7) << 4;
            af[mf][0] = *(const s16x8*)(ab + row * 128 + ((lq * 16) ^ key));
            af[mf][1] = *(const s16x8*)(ab + row * 128 + ((64 + lq * 16) ^ key));
        }
#pragma unroll
        for (int nf = 0; nf < 4; ++nf) {
            int row = wc * 64 + nf * 16 + lc;
            int key = (row & 7) << 4;
            bw[nf][0] = *(const s16x8*)(bb + row * 128 + ((lq * 16) ^ key));
            bw[nf][1] = *(const s16x8*)(bb + row * 128 + ((64 + lq * 16) ^ key));
        }
#pragma unroll
        for (int mf = 0; mf < 4; ++mf)
#pragma unroll
            for (int nf = 0; nf < 4; ++nf) {
                acc[mf][nf] = mfma_bf16(af[mf][0], bw[nf][0], acc[mf][nf]);
                acc[mf][nf] = mfma_bf16(af[mf][1], bw[nf][1], acc[mf][nf]);
            }
    }
#pragma unroll
    for (int mf = 0; mf < 4; ++mf)
#pragma unroll
        for (int nf = 0; nf < 4; ++nf) {
            int grow0 = m0 + wr * 64 + mf * 16 + lq * 4;
            int gcol = n0 + wc * 64 + nf * 16 + lc;
            int b = grow0 >> 11, nb = grow0 & 2047;
            if (EPI == 0) {
                int h = gcol >> 6, d = gcol & 63;
#pragma unroll
                for (int r = 0; r < 4; ++r)
                    o0[((size_t)((b * 8 + h) * 2048 + nb + r)) * 64 + d] =
                        f2bf(acc[mf][nf][r] * 0.125f);
            } else if (gcol < 512) {
                int h = gcol >> 6, d = gcol & 63;
#pragma unroll
                for (int r = 0; r < 4; ++r)
                    o0[((size_t)((b * 8 + h) * 2048 + nb + r)) * 64 + d] = f2bf(acc[mf][nf][r]);
            } else {
                int jj = gcol & 511;
                int h = jj >> 6, d = jj & 63;
                u16x4 vv;
#pragma unroll
                for (int r = 0; r < 4; ++r) vv[r] = f2bf(acc[mf][nf][r]);
                *(u16x4*)(o1 + ((size_t)((b * 8 + h) * 64 + d)) * 2048 + nb) = vv;
            }
        }
}

// ---------------- K4: flash attention + ablation variants -------------------
template<int V>
__launch_bounds__(256, 4)
__global__ void k_attn_t(const unsigned short* __restrict__ qg, const unsigned short* __restrict__ kg,
                         const unsigned short* __restrict__ vt, const float* __restrict__ bias,
                         const float* __restrict__ seq_mask,
                         float* __restrict__ po, float* __restrict__ ml,
                         float* __restrict__ sink_buf) {
    __shared__ unsigned short k_ring[2][64 * 64];
    __shared__ unsigned short v_ring[2][64 * 64];
    __shared__ unsigned short p_lds[4][16 * 64];

    int tid = threadIdx.x, lane = tid & 63, w = tid >> 6;
    int lc = lane & 15, lq = lane >> 4;

    int lin = blockIdx.x;
    int vid = (lin & 7) * 128 + (lin >> 3);
    int bh = vid >> 6;
    int rem = vid & 63;
    int half = rem >> 5;
    int q0 = (rem & 31) * 64 + w * 16;
    int b = bh >> 3;

    const float* bq = bias + ((size_t)bh * 2048 + q0 + lc) * 2048 + half * 1024;

    // keep LDS footprint identical across variants (occupancy parity)
    if (lin < 0) { k_ring[0][0] = 1; v_ring[0][0] = 1; p_lds[0][0] = 1; }

    if constexpr (V == 3) {
        // ---- deep-MLP bias stream: 16 independent loads in flight ----
        float sink = 0.f;
        for (int rep = 0; rep < 5; ++rep) {
            for (int kt = 0; kt < 16; kt += 4) {
                f32x4 vv[16];
#pragma unroll
                for (int j = 0; j < 4; ++j)
#pragma unroll
                    for (int nf = 0; nf < 4; ++nf)
                        vv[j * 4 + nf] = *(const f32x4*)(bq + (size_t)(kt + j) * 64 +
                                                         nf * 16 + lq * 4);
#pragma unroll
                for (int j = 0; j < 16; ++j)
                    sink += vv[j][0] + vv[j][1] + vv[j][2] + vv[j][3];
            }
        }
        sink_buf[(size_t)lin * 256 + tid] = sink;
        return;
    }

    if constexpr (V == 2) {
        // ---- structured bias stream: V0's ping-pong + barrier cadence ----
        float sink = 0.f;
        f32x4 bA[4], bB[4];
        for (int rep = 0; rep < 5; ++rep) {
#pragma unroll
            for (int nf = 0; nf < 4; ++nf)
                bA[nf] = *(const f32x4*)(bq + nf * 16 + lq * 4);
            for (int t = 0; t < 8; ++t) {
                {
                    int tk = 2 * t + 1;
#pragma unroll
                    for (int nf = 0; nf < 4; ++nf)
                        bB[nf] = *(const f32x4*)(bq + (size_t)tk * 64 + nf * 16 + lq * 4);
#pragma unroll
                    for (int nf = 0; nf < 4; ++nf)
                        sink += bA[nf][0] + bA[nf][1] + bA[nf][2] + bA[nf][3];
                    __builtin_amdgcn_s_barrier();
                }
                {
                    int tk = 2 * t + 2 < 16 ? 2 * t + 2 : 15;
#pragma unroll
                    for (int nf = 0; nf < 4; ++nf)
                        bA[nf] = *(const f32x4*)(bq + (size_t)tk * 64 + nf * 16 + lq * 4);
#pragma unroll
                    for (int nf = 0; nf < 4; ++nf)
                        sink += bB[nf][0] + bB[nf][1] + bB[nf][2] + bB[nf][3];
                    __builtin_amdgcn_s_barrier();
                }
            }
        }
        sink_buf[(size_t)lin * 256 + tid] = sink;
        return;
    }

    // ---- V0 (full, real) / V1 (no-bias) ----
    constexpr bool BIAS = (V == 0);
    constexpr int REP = (V == 0) ? 1 : 6;

    const unsigned short* qbase = qg + ((size_t)bh * 2048 + q0) * 64;
    s16x8 aq0 = *(const s16x8*)(qbase + lc * 64 + lq * 8);
    s16x8 aq1 = *(const s16x8*)(qbase + lc * 64 + 32 + lq * 8);

    const unsigned short* kb = kg + ((size_t)bh * 2048 + half * 1024) * 64;
    const unsigned short* vt0 = vt + (size_t)bh * 64 * 2048;
    const float* sk = seq_mask + b * 2048 + half * 1024;
    float qm = seq_mask[b * 2048 + q0 + lc];

    char* pw = (char*)(&p_lds[w][0]);
    int swz = (lc & 7) << 4;

    auto issue_k = [&](int tile, int slot) {
#pragma unroll
        for (int i = 0; i < 2; ++i) {
            int off = w * 2048 + i * 1024 + lane * 16;
            int row = off >> 7;
            int cc = ((off >> 4) & 7) ^ (row & 7);
            gl_lds16(kb + ((size_t)tile * 64 + row) * 64 + cc * 8,
                     (char*)k_ring[slot] + w * 2048 + i * 1024);
        }
    };
    auto issue_vt = [&](int tile, int slot) {
#pragma unroll
        for (int i = 0; i < 2; ++i) {
            int off = w * 2048 + i * 1024 + lane * 16;
            int row = off >> 7;
            int cc = ((off >> 4) & 7) ^ (row & 7);
            gl_lds16(vt0 + (size_t)row * 2048 + half * 1024 + tile * 64 + cc * 8,
                     (char*)v_ring[slot] + w * 2048 + i * 1024);
        }
    };

    float mst, lst;
    f32x4 acc[4];
    f32x4 brA[4], brB[4];

    for (int rep = 0; rep < REP; ++rep) {
        mst = -1e30f; lst = 0.f;
#pragma unroll
        for (int df = 0; df < 4; ++df)
#pragma unroll
            for (int e = 0; e < 4; ++e) acc[df][e] = 0.f;

        issue_k(0, 0);
        issue_vt(0, 0);
        __builtin_amdgcn_sched_barrier(0);
        if constexpr (BIAS) {
#pragma unroll
            for (int nf = 0; nf < 4; ++nf)
                brA[nf] = *(const f32x4*)(bq + nf * 16 + lq * 4);
        }
        __builtin_amdgcn_sched_barrier(0);
        asm volatile("s_waitcnt vmcnt(4)");
        __builtin_amdgcn_s_barrier();
        __builtin_amdgcn_sched_barrier(0);

        auto iter = [&](int kt, int par, f32x4 (&cur)[4], f32x4 (&nxt)[4]) {
            const int slot_nxt = par ^ 1;
            const char* klds = (const char*)k_ring[par];
            f32x4 sv[4];
            __builtin_amdgcn_s_setprio(1);
#pragma unroll
            for (int nf = 0; nf < 4; ++nf) {
                int row = nf * 16 + lc;
                s16x8 b0 = *(const s16x8*)(klds + row * 128 + ((lq * 16) ^ swz));
                s16x8 b1 = *(const s16x8*)(klds + row * 128 + ((64 + lq * 16) ^ swz));
                f32x4 z;
                z[0] = 0.f; z[1] = 0.f; z[2] = 0.f; z[3] = 0.f;
                z = mfma_bf16(b0, aq0, z);
                z = mfma_bf16(b1, aq1, z);
                sv[nf] = z;
            }
            __builtin_amdgcn_s_setprio(0);

#pragma unroll
            for (int nf = 0; nf < 4; ++nf) {
                f32x4 km = *(const f32x4*)(sk + kt * 64 + nf * 16 + lq * 4);
                if constexpr (BIAS)
                    sv[nf] = sv[nf] + cur[nf] + (km * qm - 1.f) * NEGV;
                else
                    sv[nf] = sv[nf] + (km * qm - 1.f) * NEGV;
            }
            __builtin_amdgcn_sched_barrier(0);

            {
                int tk = (kt + 1 < 16) ? kt + 1 : 15;
                issue_k(tk, slot_nxt);
                issue_vt(tk, slot_nxt);
                if constexpr (BIAS) {
#pragma unroll
                    for (int nf = 0; nf < 4; ++nf)
                        nxt[nf] = *(const f32x4*)(bq + (size_t)tk * 64 + nf * 16 + lq * 4);
                }
            }
            __builtin_amdgcn_sched_barrier(0);

            f32x4 m4 = sv[0];
#pragma unroll
            for (int nf = 1; nf < 4; ++nf)
#pragma unroll
                for (int e = 0; e < 4; ++e) m4[e] = fmaxf(m4[e], sv[nf][e]);
            float mx = fmaxf(fmaxf(m4[0], m4[1]), fmaxf(m4[2], m4[3]));
            mx = fmaxf(mx, __shfl_xor(mx, 16));
            mx = fmaxf(mx, __shfl_xor(mx, 32));
            float mn = fmaxf(mst, mx);
            float scl = __expf(mst - mn);
            mst = mn;
            float rsum = 0.f;
#pragma unroll
            for (int nf = 0; nf < 4; ++nf) {
                f32x4 p;
#pragma unroll
                for (int e = 0; e < 4; ++e) { p[e] = __expf(sv[nf][e] - mn); rsum += p[e]; }
                unsigned int w0 = ((unsigned)f2bf(p[1]) << 16) | f2bf(p[0]);
                unsigned int w1 = ((unsigned)f2bf(p[3]) << 16) | f2bf(p[2]);
                *(unsigned int*)(pw + lc * 128 + ((nf * 32 + lq * 8) ^ swz)) = w0;
                *(unsigned int*)(pw + lc * 128 + ((nf * 32 + lq * 8 + 4) ^ swz)) = w1;
            }
            rsum += __shfl_xor(rsum, 16);
            rsum += __shfl_xor(rsum, 32);
            lst = lst * scl + rsum;
#pragma unroll
            for (int df = 0; df < 4; ++df)
#pragma unroll
                for (int e = 0; e < 4; ++e) acc[df][e] *= scl;

            __builtin_amdgcn_sched_barrier(0);
            asm volatile("s_waitcnt lgkmcnt(0)");
            __builtin_amdgcn_sched_barrier(0);

            s16x8 ap0 = *(const s16x8*)(pw + lc * 128 + ((lq * 16) ^ swz));
            s16x8 ap1 = *(const s16x8*)(pw + lc * 128 + ((64 + lq * 16) ^ swz));
            const char* vlds = (const char*)v_ring[par];
            __builtin_amdgcn_s_setprio(1);
#pragma unroll
            for (int df = 0; df < 4; ++df) {
                int row = df * 16 + lc;
                int key = (row & 7) << 4;
                s16x8 av0 = *(const s16x8*)(vlds + row * 128 + ((lq * 16) ^ key));
                s16x8 av1 = *(const s16x8*)(vlds + row * 128 + ((64 + lq * 16) ^ key));
                acc[df] = mfma_bf16(av0, ap0, acc[df]);
                acc[df] = mfma_bf16(av1, ap1, acc[df]);
            }
            __builtin_amdgcn_s_setprio(0);

            __builtin_amdgcn_sched_barrier(0);
            asm volatile("s_waitcnt vmcnt(4) lgkmcnt(0)");
            __builtin_amdgcn_s_barrier();
            __builtin_amdgcn_sched_barrier(0);
        };

        for (int t = 0; t < 8; ++t) {
            iter(2 * t,     0, brA, brB);
            iter(2 * t + 1, 1, brB, brA);
        }
        asm volatile("s_waitcnt vmcnt(0)");
    }

    float* prow = po + ((size_t)((half * 16 + bh) * 2048) + q0 + lc) * 64;
#pragma unroll
    for (int df = 0; df < 4; ++df)
        *(f32x4*)(prow + df * 16 + lq * 4) = acc[df];
    if (lq == 0) {
        int r = (half * 16 + bh) * 2048 + q0 + lc;
        ml[2 * r] = mst;
        ml[2 * r + 1] = lst;
    }
}

// ---------------- K4b: merge key-halves -> ah/al (hi/lo bf16 split) ---------
__global__ void k_comb(const float* __restrict__ po, const float* __restrict__ ml,
                       unsigned short* __restrict__ ah, unsigned short* __restrict__ al) {
    int g = blockIdx.x * 256 + threadIdx.x;   // 131072 = 32768 rows x 4 chunks
    int row = g >> 2, ch = g & 3;
    int bh = row >> 11, q = row & 2047;
    int b = bh >> 3, h = bh & 7;
    float m0 = ml[2 * row],           l0 = ml[2 * row + 1];
    float m1 = ml[2 * (row + 32768)], l1 = ml[2 * (row + 32768) + 1];
    float m = fmaxf(m0, m1);
    float e0 = __expf(m0 - m), e1 = __expf(m1 - m);
    float inv = 1.f / (e0 * l0 + e1 * l1);
    const float* p0 = po + (size_t)row * 64 + ch * 16;
    const float* p1 = p0 + (size_t)32768 * 64;
    size_t ob = ((size_t)(b * 2048 + q)) * 512 + h * 64 + ch * 16;
#pragma unroll
    for (int i = 0; i < 4; ++i) {
        f32x4 a0 = *(const f32x4*)(p0 + i * 4);
        f32x4 a1 = *(const f32x4*)(p1 + i * 4);
        u16x4 hi, lo;
#pragma unroll
        for (int e = 0; e < 4; ++e) {
            float o = (e0 * a0[e] + e1 * a1[e]) * inv;
            unsigned short hb = f2bf(o);
            hi[e] = hb;
            lo[e] = f2bf(o - bf2f(hb));
        }
        *(u16x4*)(ah + ob + i * 4) = hi;
        *(u16x4*)(al + ob + i * 4) = lo;
    }
}

// ---------------- K5: out = (Ah+Al)(Wh+Wl)^T * seq_mask  (3-term split) -----
__launch_bounds__(256)
__global__ void k_gemm_out(const unsigned short* __restrict__ Ah, const unsigned short* __restrict__ Al,
                           const unsigned short* __restrict__ Wh, const unsigned short* __restrict__ Wl,
                           const float* __restrict__ seq_mask, float* __restrict__ out) {
    __shared__ unsigned short ah_t[128 * 32], al_t[128 * 32], bh_t[128 * 32], bl_t[128 * 32];
    int tid = threadIdx.x, lane = tid & 63, wid = tid >> 6;
    int lc = lane & 15, lq = lane >> 4;
    int wr = wid >> 1, wc = wid & 1;
    int m0 = blockIdx.x * 128, n0 = blockIdx.y * 128;
    f32x4 acc[4][4];
#pragma unroll
    for (int i = 0; i < 4; ++i)
#pragma unroll
        for (int jn = 0; jn < 4; ++jn)
#pragma unroll
            for (int e = 0; e < 4; ++e) acc[i][jn][e] = 0.f;
    int wbase = wid * 64;
    for (int kt = 0; kt < 16; ++kt) {
        __syncthreads();
#pragma unroll
        for (int i = 0; i < 2; ++i) {
            int p = i * 256 + wbase + lane;
            int row = p >> 2, ls = (p & 3) ^ (row & 3);
            size_t asrc = (size_t)(m0 + row) * 512 + kt * 32 + ls * 8;
            size_t bsrc = (size_t)(n0 + row) * 512 + kt * 32 + ls * 8;
            int dst = (i * 256 + wbase) * 8;
            gl_lds16(Ah + asrc, ah_t + dst);
            gl_lds16(Al + asrc, al_t + dst);
            gl_lds16(Wh + bsrc, bh_t + dst);
            gl_lds16(Wl + bsrc, bl_t + dst);
        }
        __syncthreads();
        s16x8 fah[4], fal[4], fbh[4], fbl[4];
#pragma unroll
        for (int mf = 0; mf < 4; ++mf) {
            int row = wr * 64 + mf * 16 + lc;
            int off = row * 64 + ((lq * 16) ^ ((row & 3) << 4));
            fah[mf] = *(const s16x8*)((const char*)ah_t + off);
            fal[mf] = *(const s16x8*)((const char*)al_t + off);
        }
#pragma unroll
        for (int nf = 0; nf < 4; ++nf) {
            int row = wc * 64 + nf * 16 + lc;
            int off = row * 64 + ((lq * 16) ^ ((row & 3) << 4));
            fbh[nf] = *(const s16x8*)((const char*)bh_t + off);
            fbl[nf] = *(const s16x8*)((const char*)bl_t + off);
        }
#pragma unroll
        for (int mf = 0; mf < 4; ++mf)
#pragma unroll
            for (int nf = 0; nf < 4; ++nf) {
                acc[mf][nf] = mfma_bf16(fah[mf], fbh[nf], acc[mf][nf]);
                acc[mf][nf] = mfma_bf16(fah[mf], fbl[nf], acc[mf][nf]);
                acc[mf][nf] = mfma_bf16(fal[mf], fbh[nf], acc[mf][nf]);
            }
    }
#pragma unroll
    for (int mf = 0; mf < 4; ++mf)
#pragma unroll
        for (int nf = 0; nf < 4; ++nf)
#pragma unroll
            for (int r = 0; r < 4; ++r) {
                int grow = m0 + wr * 64 + mf * 16 + lq * 4 + r;
                int gcol = n0 + wc * 64 + nf * 16 + lc;
                out[(size_t)grow * 512 + gcol] = acc[mf][nf][r] * seq_mask[grow];
            }
}

// ---------------------------------------------------------------------------
extern "C" void kernel_launch(void* const* d_in, const int* in_sizes, int n_in,
                              void* d_out, int out_size, void* d_ws, size_t ws_size,
                              hipStream_t stream) {
    const float* x         = (const float*)d_in[0];
    const float* timev     = (const float*)d_in[1];
    const float* attn_bias = (const float*)d_in[2];
    const float* seq_mask  = (const float*)d_in[3];
    const float* gamma     = (const float*)d_in[4];
    const float* w_time    = (const float*)d_in[5];
    const float* b_time    = (const float*)d_in[6];
    const float* w_q       = (const float*)d_in[7];
    const float* w_kv      = (const float*)d_in[8];
    const float* w_out     = (const float*)d_in[9];
    float* out = (float*)d_out;

    char* ws = (char*)d_ws;
    size_t off = 0;
    auto alloc = [&](size_t bytes) {
        char* p = ws + off;
        off += (bytes + 255) & ~(size_t)255;
        return p;
    };
    float*          tc   = (float*)alloc(2048 * 4);
    unsigned short* wq   = (unsigned short*)alloc(262144 * 2);
    unsigned short* wkv  = (unsigned short*)alloc(524288 * 2);
    unsigned short* wo_h = (unsigned short*)alloc(262144 * 2);
    unsigned short* wo_l = (unsigned short*)alloc(262144 * 2);
    unsigned short* xbf  = (unsigned short*)alloc(2097152 * 2);
    unsigned short* xnbf = (unsigned short*)alloc(2097152 * 2);
    unsigned short* qb   = (unsigned short*)alloc(2097152 * 2);
    unsigned short* kb   = (unsigned short*)alloc(2097152 * 2);
    unsigned short* vtb  = (unsigned short*)alloc(2097152 * 2);
    unsigned short* ahh  = (unsigned short*)alloc(2097152 * 2);
    unsigned short* all_ = (unsigned short*)alloc(2097152 * 2);
    float*          po   = (float*)alloc((size_t)2 * 16 * 2048 * 64 * 4);  // 16.8MB
    float*          ml   = (float*)alloc((size_t)2 * 16 * 2048 * 2 * 4);   // 0.5MB
    float*          sinkb= (float*)alloc((size_t)1024 * 256 * 4);          // 1MB

    k_prep<<<4096, 256, 0, stream>>>(w_q, w_kv, w_out, wq, wkv, wo_h, wo_l);
    k_time<<<512, 256, 0, stream>>>(timev, w_time, b_time, tc);
    k_lnfilm<<<4096, 256, 0, stream>>>(x, gamma, seq_mask, tc, xbf, xnbf);
    k_gemm<0><<<dim3(32, 4), 256, 0, stream>>>(xnbf, wq, qb, nullptr);
    k_gemm<1><<<dim3(32, 8), 256, 0, stream>>>(xbf, wkv, kb, vtb);
    // --- ablation probes (scratch only; V0 below overwrites po/ml fully) ---
    k_attn_t<3><<<1024, 256, 0, stream>>>(qb, kb, vtb, attn_bias, seq_mask, po, ml, sinkb);
    k_attn_t<2><<<1024, 256, 0, stream>>>(qb, kb, vtb, attn_bias, seq_mask, po, ml, sinkb);
    k_attn_t<1><<<1024, 256, 0, stream>>>(qb, kb, vtb, attn_bias, seq_mask, po, ml, sinkb);
    // --- real attention ---
    k_attn_t<0><<<1024, 256, 0, stream>>>(qb, kb, vtb, attn_bias, seq_mask, po, ml, sinkb);
    k_comb<<<512, 256, 0, stream>>>(po, ml, ahh, all_);
    k_gemm_out<<<dim3(32, 4), 256, 0, stream>>>(ahh, all_, wo_h, wo_l, seq_mask, out);
}

// Round 10
// 162.527 us; speedup vs baseline: 2.7809x; 2.7809x over previous
//
#include <hip/hip_runtime.h>
#include <stdint.h>

// ---------------------------------------------------------------------------
// TimeCondAttention on MI355X (gfx950)
// B=2, N=2048, DIM=512, H=8, DH=64, TIME_DIM=512
// R10: R9 with the mask-arithmetic precision fix:
//   - penalty = fma(km, qm, -1) * NEG2  (exact 0 unmasked; never mixes 1e6
//     into S at f32 ulp 0.125 — R9's failure cause)
//   - keeps: log2-domain softmax + exp2, defer-max, cvt_pk P-store,
//     prefetch-at-top, key-split x2 + k_comb, 4 blocks/CU
// ---------------------------------------------------------------------------

using s16x8 = __attribute__((ext_vector_type(8))) short;
using f32x4 = __attribute__((ext_vector_type(4))) float;
using u16x4 = __attribute__((ext_vector_type(4))) unsigned short;
using u32x2 = __attribute__((ext_vector_type(2))) unsigned int;

#define EPSV 1e-5f
#define NEGV 1e6f
#define L2E  1.44269504088896341f
// q-projection scale: 0.125 * log2(e)
#define QSCL 0.18033688011112043f

__device__ __forceinline__ unsigned short f2bf(float f) {
    unsigned int u = __float_as_uint(f);
    u += 0x7FFFu + ((u >> 16) & 1u);   // RNE (inputs finite)
    return (unsigned short)(u >> 16);
}
__device__ __forceinline__ float bf2f(unsigned short s) {
    return __uint_as_float((unsigned int)s << 16);
}

__device__ __forceinline__ void gl_lds16(const void* g, void* l) {
    __builtin_amdgcn_global_load_lds((const __attribute__((address_space(1))) void*)g,
                                     (__attribute__((address_space(3))) void*)l, 16, 0, 0);
}

__device__ __forceinline__ f32x4 mfma_bf16(s16x8 a, s16x8 b, f32x4 c) {
    return __builtin_amdgcn_mfma_f32_16x16x32_bf16(a, b, c, 0, 0, 0);
}

// ---------------- K0: weight conversion (w_q, w_kv bf16; w_out hi/lo split) --
__global__ void k_prep(const float* __restrict__ w_q, const float* __restrict__ w_kv,
                       const float* __restrict__ w_out,
                       unsigned short* __restrict__ wq, unsigned short* __restrict__ wkv,
                       unsigned short* __restrict__ wo_h, unsigned short* __restrict__ wo_l) {
    int idx = blockIdx.x * 256 + threadIdx.x;         // total 1,048,576 exactly
    if (idx < 262144) {
        wq[idx] = f2bf(w_q[idx]);
    } else if (idx < 786432) {
        int i = idx - 262144;
        wkv[i] = f2bf(w_kv[i]);
    } else {
        int i = idx - 786432;
        float v = w_out[i];
        unsigned short h = f2bf(v);
        wo_h[i] = h;
        wo_l[i] = f2bf(v - bf2f(h));
    }
}

// ---------------- K1: t = silu(time) @ w_time.T + b_time  ([2][1024] f32) ----
__global__ void k_time(const float* __restrict__ timev, const float* __restrict__ w_time,
                       const float* __restrict__ b_time, float* __restrict__ tc) {
    int wid = threadIdx.x >> 6, lane = threadIdx.x & 63;
    int b = blockIdx.x >> 8;
    int j = (blockIdx.x & 255) * 4 + wid;             // 0..1023
    const float* tv = timev + b * 512;
    const float* wr = w_time + (size_t)j * 512;
    float acc = 0.f;
#pragma unroll
    for (int i = 0; i < 8; ++i) {
        int k = i * 64 + lane;
        float t = tv[k];
        float s = t / (1.f + __expf(-t));             // silu
        acc += s * wr[k];
    }
#pragma unroll
    for (int m = 32; m >= 1; m >>= 1) acc += __shfl_xor(acc, m);
    if (lane == 0) tc[b * 1024 + j] = acc + b_time[j];
}

// ---------------- K2: LayerNorm + FiLM + seq_mask -> xn(bf16); x -> bf16 -----
__global__ void k_lnfilm(const float* __restrict__ x, const float* __restrict__ gamma,
                         const float* __restrict__ seq_mask, const float* __restrict__ tc,
                         unsigned short* __restrict__ xbf, unsigned short* __restrict__ xnbf) {
    int row = blockIdx.x;                             // b*2048 + n
    int b = row >> 11;
    int tid = threadIdx.x, wid = tid >> 6, lane = tid & 63;
    float2 xv = *(const float2*)(x + (size_t)row * 512 + tid * 2);
    float s = xv.x + xv.y;
    float sq = xv.x * xv.x + xv.y * xv.y;
#pragma unroll
    for (int m = 32; m >= 1; m >>= 1) { s += __shfl_xor(s, m); sq += __shfl_xor(sq, m); }
    __shared__ float red[8];
    if (lane == 0) { red[wid] = s; red[wid + 4] = sq; }
    __syncthreads();
    float ts = red[0] + red[1] + red[2] + red[3];
    float tq = red[4] + red[5] + red[6] + red[7];
    float mu = ts * (1.f / 512.f);
    float var = tq * (1.f / 512.f) - mu * mu;
    float rs = rsqrtf(var + EPSV);
    float qm = seq_mask[row];
    int j = tid * 2;
    const float* scb = tc + b * 1024;
    float o0 = ((xv.x - mu) * rs * gamma[j])     * (scb[j] + 1.f)     + scb[j + 512];
    float o1 = ((xv.y - mu) * rs * gamma[j + 1]) * (scb[j + 1] + 1.f) + scb[j + 513];
    size_t base = (size_t)row * 512 + j;
    xnbf[base]     = f2bf(o0 * qm);
    xnbf[base + 1] = f2bf(o1 * qm);
    xbf[base]      = f2bf(xv.x);
    xbf[base + 1]  = f2bf(xv.y);
}

// ---------------- K3: bf16 GEMM C = A[M,512] * W[Nout,512]^T, scatter epi ----
// EPI 0: q-proj (scale 0.125*log2e, [b,h,n,d]); EPI 1: kv (k: [b,h,n,d], v: [b,h,d,n])
template<int EPI>
__launch_bounds__(256)
__global__ void k_gemm(const unsigned short* __restrict__ A, const unsigned short* __restrict__ W,
                       unsigned short* __restrict__ o0, unsigned short* __restrict__ o1) {
    __shared__ unsigned short a_t[128 * 64];
    __shared__ unsigned short b_t[128 * 64];
    int tid = threadIdx.x, lane = tid & 63, wid = tid >> 6;
    int lc = lane & 15, lq = lane >> 4;
    int wr = wid >> 1, wc = wid & 1;
    int m0 = blockIdx.x * 128, n0 = blockIdx.y * 128;
    f32x4 acc[4][4];
#pragma unroll
    for (int i = 0; i < 4; ++i)
#pragma unroll
        for (int jn = 0; jn < 4; ++jn)
#pragma unroll
            for (int e = 0; e < 4; ++e) acc[i][jn][e] = 0.f;
    const unsigned short* Ab = A + (size_t)m0 * 512;
    const unsigned short* Wb = W + (size_t)n0 * 512;
    int wbase = wid * 64;
    for (int kt = 0; kt < 8; ++kt) {
        __syncthreads();
#pragma unroll
        for (int i = 0; i < 4; ++i) {
            int p = i * 256 + wbase + lane;
            int row = p >> 3, ls = (p & 7) ^ (row & 7);
            gl_lds16(Ab + (size_t)row * 512 + kt * 64 + ls * 8, a_t + (i * 256 + wbase) * 8);
            gl_lds16(Wb + (size_t)row * 512 + kt * 64 + ls * 8, b_t + (i * 256 + wbase) * 8);
        }
        __syncthreads();
        s16x8 af[4][2], bw[4][2];
        const char* ab = (const char*)a_t;
        const char* bb = (const char*)b_t;
#pragma unroll
        for (int mf = 0; mf < 4; ++mf) {
            int row = wr * 64 + mf * 16 + lc;
            int key = (row & 7) << 4;
            af[mf][0] = *(const s16x8*)(ab + row * 128 + ((lq * 16) ^ key));
            af[mf][1] = *(const s16x8*)(ab + row * 128 + ((64 + lq * 16) ^ key));
        }
#pragma unroll
        for (int nf = 0; nf < 4; ++nf) {
            int row = wc * 64 + nf * 16 + lc;
            int key = (row & 7) << 4;
            bw[nf][0] = *(const s16x8*)(bb + row * 128 + ((lq * 16) ^ key));
            bw[nf][1] = *(const s16x8*)(bb + row * 128 + ((64 + lq * 16) ^ key));
        }
#pragma unroll
        for (int mf = 0; mf < 4; ++mf)
#pragma unroll
            for (int nf = 0; nf < 4; ++nf) {
                acc[mf][nf] = mfma_bf16(af[mf][0], bw[nf][0], acc[mf][nf]);
                acc[mf][nf] = mfma_bf16(af[mf][1], bw[nf][1], acc[mf][nf]);
            }
    }
#pragma unroll
    for (int mf = 0; mf < 4; ++mf)
#pragma unroll
        for (int nf = 0; nf < 4; ++nf) {
            int grow0 = m0 + wr * 64 + mf * 16 + lq * 4;
            int gcol = n0 + wc * 64 + nf * 16 + lc;
            int b = grow0 >> 11, nb = grow0 & 2047;
            if (EPI == 0) {
                int h = gcol >> 6, d = gcol & 63;
#pragma unroll
                for (int r = 0; r < 4; ++r)
                    o0[((size_t)((b * 8 + h) * 2048 + nb + r)) * 64 + d] =
                        f2bf(acc[mf][nf][r] * QSCL);
            } else if (gcol < 512) {
                int h = gcol >> 6, d = gcol & 63;
#pragma unroll
                for (int r = 0; r < 4; ++r)
                    o0[((size_t)((b * 8 + h) * 2048 + nb + r)) * 64 + d] = f2bf(acc[mf][nf][r]);
            } else {
                int jj = gcol & 511;
                int h = jj >> 6, d = jj & 63;
                u16x4 vv;
#pragma unroll
                for (int r = 0; r < 4; ++r) vv[r] = f2bf(acc[mf][nf][r]);
                *(u16x4*)(o1 + ((size_t)((b * 8 + h) * 64 + d)) * 2048 + nb) = vv;
            }
        }
}

// ---------------- K4: flash attention, VALU-diet, key-split ----------------
__launch_bounds__(256, 4)
__global__ void k_attn(const unsigned short* __restrict__ qg, const unsigned short* __restrict__ kg,
                       const unsigned short* __restrict__ vt, const float* __restrict__ bias,
                       const float* __restrict__ seq_mask,
                       float* __restrict__ po, float* __restrict__ ml) {
    __shared__ unsigned short k_ring[2][64 * 64];   // [key][d] swizzled, 8KB/slot
    __shared__ unsigned short v_ring[2][64 * 64];   // [d][key] swizzled, 8KB/slot
    __shared__ unsigned short p_lds[4][16 * 64];    // per-wave P, 2KB/wave

    int tid = threadIdx.x, lane = tid & 63, w = tid >> 6;
    int lc = lane & 15, lq = lane >> 4;

    // XCD mapping: 1024 blocks; XCD c hosts bh {2c,2c+1} (K/V L2-resident)
    int lin = blockIdx.x;
    int vid = (lin & 7) * 128 + (lin >> 3);
    int bh = vid >> 6;
    int rem = vid & 63;
    int half = rem >> 5;
    int q0 = (rem & 31) * 64 + w * 16;
    int b = bh >> 3;

    const unsigned short* qbase = qg + ((size_t)bh * 2048 + q0) * 64;
    s16x8 aq0 = *(const s16x8*)(qbase + lc * 64 + lq * 8);
    s16x8 aq1 = *(const s16x8*)(qbase + lc * 64 + 32 + lq * 8);

    const unsigned short* kb = kg + ((size_t)bh * 2048 + half * 1024) * 64;
    const unsigned short* vt0 = vt + (size_t)bh * 64 * 2048;
    const float* bq = bias + ((size_t)bh * 2048 + q0 + lc) * 2048 + half * 1024;
    const float* sk = seq_mask + b * 2048 + half * 1024;
    const float NEG2 = NEGV * L2E;
    float qm_ = seq_mask[b * 2048 + q0 + lc];

    char* pw = (char*)(&p_lds[w][0]);
    int swz = (lc & 7) << 4;

    float mst = -1e30f, lst = 0.f;
    f32x4 acc[4];
#pragma unroll
    for (int df = 0; df < 4; ++df)
#pragma unroll
        for (int e = 0; e < 4; ++e) acc[df][e] = 0.f;

    auto issue_k = [&](int tile, int slot) {
#pragma unroll
        for (int i = 0; i < 2; ++i) {
            int off = w * 2048 + i * 1024 + lane * 16;
            int row = off >> 7;
            int cc = ((off >> 4) & 7) ^ (row & 7);
            gl_lds16(kb + ((size_t)tile * 64 + row) * 64 + cc * 8,
                     (char*)k_ring[slot] + w * 2048 + i * 1024);
        }
    };
    auto issue_vt = [&](int tile, int slot) {
#pragma unroll
        for (int i = 0; i < 2; ++i) {
            int off = w * 2048 + i * 1024 + lane * 16;
            int row = off >> 7;
            int cc = ((off >> 4) & 7) ^ (row & 7);
            gl_lds16(vt0 + (size_t)row * 2048 + half * 1024 + tile * 64 + cc * 8,
                     (char*)v_ring[slot] + w * 2048 + i * 1024);
        }
    };

    f32x4 brA[4], brB[4];

    // ---- prologue: KV(0)->slot0 [4 vm]; bias(0)->brA [4 vm]; wait KV ----
    issue_k(0, 0);
    issue_vt(0, 0);
    __builtin_amdgcn_sched_barrier(0);
#pragma unroll
    for (int nf = 0; nf < 4; ++nf)
        brA[nf] = *(const f32x4*)(bq + nf * 16 + lq * 4);
    __builtin_amdgcn_sched_barrier(0);
    asm volatile("s_waitcnt vmcnt(4)");
    __builtin_amdgcn_s_barrier();
    __builtin_amdgcn_sched_barrier(0);

    auto iter = [&](int kt, int par, f32x4 (&cur)[4], f32x4 (&nxt)[4]) {
        const int slot_nxt = par ^ 1;

        // ---- phase 0: km loads FIRST (oldest -> counted waits never drain) ----
        f32x4 km[4];
#pragma unroll
        for (int nf = 0; nf < 4; ++nf)
            km[nf] = *(const f32x4*)(sk + kt * 64 + nf * 16 + lq * 4);
        __builtin_amdgcn_sched_barrier(0);

        // ---- phase A/B: prefetch KV(kt+1) -> slot nxt; bias(kt+1) -> nxt ----
        {
            int tk = (kt + 1 < 16) ? kt + 1 : 15;
            issue_k(tk, slot_nxt);
            issue_vt(tk, slot_nxt);
#pragma unroll
            for (int nf = 0; nf < 4; ++nf)
                nxt[nf] = *(const f32x4*)(bq + (size_t)tk * 64 + nf * 16 + lq * 4);
        }
        __builtin_amdgcn_sched_barrier(0);

        // ---- phase C: S^T = K Q^T (log2-domain: q pre-scaled by 0.125*log2e) ----
        const char* klds = (const char*)k_ring[par];
        f32x4 sv[4];
        __builtin_amdgcn_s_setprio(1);
#pragma unroll
        for (int nf = 0; nf < 4; ++nf) {
            int row = nf * 16 + lc;
            s16x8 b0 = *(const s16x8*)(klds + row * 128 + ((lq * 16) ^ swz));
            s16x8 b1 = *(const s16x8*)(klds + row * 128 + ((64 + lq * 16) ^ swz));
            f32x4 z;
            z[0] = 0.f; z[1] = 0.f; z[2] = 0.f; z[3] = 0.f;
            z = mfma_bf16(b0, aq0, z);
            z = mfma_bf16(b1, aq1, z);
            sv[nf] = z;
        }
        __builtin_amdgcn_s_setprio(0);

        // ---- phase D: bias*log2e + mask penalty (exact 0 when unmasked) ----
#pragma unroll
        for (int nf = 0; nf < 4; ++nf) {
#pragma unroll
            for (int e = 0; e < 4; ++e) {
                float pen = __builtin_fmaf(km[nf][e], qm_, -1.0f) * NEG2;
                sv[nf][e] = __builtin_fmaf(cur[nf][e], L2E, sv[nf][e]) + pen;
            }
        }

        // ---- phase E: online softmax, defer-max (THR = 8 nats in log2) ----
        f32x4 m4 = sv[0];
#pragma unroll
        for (int nf = 1; nf < 4; ++nf)
#pragma unroll
            for (int e = 0; e < 4; ++e) m4[e] = fmaxf(m4[e], sv[nf][e]);
        float mx = fmaxf(fmaxf(m4[0], m4[1]), fmaxf(m4[2], m4[3]));
        mx = fmaxf(mx, __shfl_xor(mx, 16));
        mx = fmaxf(mx, __shfl_xor(mx, 32));
        if (!__all(mx <= mst + 11.54f)) {
            float mn = fmaxf(mst, mx);
            float scl = __builtin_amdgcn_exp2f(mst - mn);
            lst *= scl;
#pragma unroll
            for (int df = 0; df < 4; ++df)
#pragma unroll
                for (int e = 0; e < 4; ++e) acc[df][e] *= scl;
            mst = mn;
        }
        float rsum = 0.f;
#pragma unroll
        for (int nf = 0; nf < 4; ++nf) {
            f32x4 p;
#pragma unroll
            for (int e = 0; e < 4; ++e) {
                p[e] = __builtin_amdgcn_exp2f(sv[nf][e] - mst);
                rsum += p[e];
            }
            unsigned int pk01, pk23;
            asm("v_cvt_pk_bf16_f32 %0, %1, %2" : "=v"(pk01) : "v"(p[0]), "v"(p[1]));
            asm("v_cvt_pk_bf16_f32 %0, %1, %2" : "=v"(pk23) : "v"(p[2]), "v"(p[3]));
            u32x2 pkv;
            pkv[0] = pk01; pkv[1] = pk23;
            *(u32x2*)(pw + lc * 128 + ((nf * 32 + lq * 8) ^ swz)) = pkv;
        }
        rsum += __shfl_xor(rsum, 16);
        rsum += __shfl_xor(rsum, 32);
        lst += rsum;

        __builtin_amdgcn_sched_barrier(0);
        asm volatile("s_waitcnt lgkmcnt(0)");   // P visible (wave-local)
        __builtin_amdgcn_sched_barrier(0);      // rule #18

        // ---- phase F: O^T += V^T P^T ----
        s16x8 ap0 = *(const s16x8*)(pw + lc * 128 + ((lq * 16) ^ swz));
        s16x8 ap1 = *(const s16x8*)(pw + lc * 128 + ((64 + lq * 16) ^ swz));
        const char* vlds = (const char*)v_ring[par];
        __builtin_amdgcn_s_setprio(1);
#pragma unroll
        for (int df = 0; df < 4; ++df) {
            int row = df * 16 + lc;
            int key = (row & 7) << 4;
            s16x8 av0 = *(const s16x8*)(vlds + row * 128 + ((lq * 16) ^ key));
            s16x8 av1 = *(const s16x8*)(vlds + row * 128 + ((64 + lq * 16) ^ key));
            acc[df] = mfma_bf16(av0, ap0, acc[df]);
            acc[df] = mfma_bf16(av1, ap1, acc[df]);
        }
        __builtin_amdgcn_s_setprio(0);

        // ---- tail: KV(kt+1) landed; bias(kt+1) (newest 4) flies on ----
        __builtin_amdgcn_sched_barrier(0);
        asm volatile("s_waitcnt vmcnt(4) lgkmcnt(0)");
        __builtin_amdgcn_s_barrier();
        __builtin_amdgcn_sched_barrier(0);
    };

    for (int t = 0; t < 8; ++t) {
        iter(2 * t,     0, brA, brB);
        iter(2 * t + 1, 1, brB, brA);
    }
    asm volatile("s_waitcnt vmcnt(0)");   // retire dangling clamped prefetches

    // ---- partial output (unnormalized acc + m(log2-domain), l) ----
    float* prow = po + ((size_t)((half * 16 + bh) * 2048) + q0 + lc) * 64;
#pragma unroll
    for (int df = 0; df < 4; ++df)
        *(f32x4*)(prow + df * 16 + lq * 4) = acc[df];
    if (lq == 0) {
        int r = (half * 16 + bh) * 2048 + q0 + lc;
        ml[2 * r] = mst;
        ml[2 * r + 1] = lst;
    }
}

// ---------------- K4b: merge key-halves -> ah/al (log2-domain m) ------------
__global__ void k_comb(const float* __restrict__ po, const float* __restrict__ ml,
                       unsigned short* __restrict__ ah, unsigned short* __restrict__ al) {
    int g = blockIdx.x * 256 + threadIdx.x;   // 131072 = 32768 rows x 4 chunks
    int row = g >> 2, ch = g & 3;
    int bh = row >> 11, q = row & 2047;
    int b = bh >> 3, h = bh & 7;
    float m0 = ml[2 * row],           l0 = ml[2 * row + 1];
    float m1 = ml[2 * (row + 32768)], l1 = ml[2 * (row + 32768) + 1];
    float m = fmaxf(m0, m1);
    float e0 = __builtin_amdgcn_exp2f(m0 - m);
    float e1 = __builtin_amdgcn_exp2f(m1 - m);
    float inv = 1.f / (e0 * l0 + e1 * l1);
    const float* p0 = po + (size_t)row * 64 + ch * 16;
    const float* p1 = p0 + (size_t)32768 * 64;
    size_t ob = ((size_t)(b * 2048 + q)) * 512 + h * 64 + ch * 16;
#pragma unroll
    for (int i = 0; i < 4; ++i) {
        f32x4 a0 = *(const f32x4*)(p0 + i * 4);
        f32x4 a1 = *(const f32x4*)(p1 + i * 4);
        u16x4 hi, lo;
#pragma unroll
        for (int e = 0; e < 4; ++e) {
            float o = (e0 * a0[e] + e1 * a1[e]) * inv;
            unsigned short hb = f2bf(o);
            hi[e] = hb;
            lo[e] = f2bf(o - bf2f(hb));
        }
        *(u16x4*)(ah + ob + i * 4) = hi;
        *(u16x4*)(al + ob + i * 4) = lo;
    }
}

// ---------------- K5: out = (Ah+Al)(Wh+Wl)^T * seq_mask  (3-term split) -----
__launch_bounds__(256)
__global__ void k_gemm_out(const unsigned short* __restrict__ Ah, const unsigned short* __restrict__ Al,
                           const unsigned short* __restrict__ Wh, const unsigned short* __restrict__ Wl,
                           const float* __restrict__ seq_mask, float* __restrict__ out) {
    __shared__ unsigned short ah_t[128 * 32], al_t[128 * 32], bh_t[128 * 32], bl_t[128 * 32];
    int tid = threadIdx.x, lane = tid & 63, wid = tid >> 6;
    int lc = lane & 15, lq = lane >> 4;
    int wr = wid >> 1, wc = wid & 1;
    int m0 = blockIdx.x * 128, n0 = blockIdx.y * 128;
    f32x4 acc[4][4];
#pragma unroll
    for (int i = 0; i < 4; ++i)
#pragma unroll
        for (int jn = 0; jn < 4; ++jn)
#pragma unroll
            for (int e = 0; e < 4; ++e) acc[i][jn][e] = 0.f;
    int wbase = wid * 64;
    for (int kt = 0; kt < 16; ++kt) {
        __syncthreads();
#pragma unroll
        for (int i = 0; i < 2; ++i) {
            int p = i * 256 + wbase + lane;
            int row = p >> 2, ls = (p & 3) ^ (row & 3);
            size_t asrc = (size_t)(m0 + row) * 512 + kt * 32 + ls * 8;
            size_t bsrc = (size_t)(n0 + row) * 512 + kt * 32 + ls * 8;
            int dst = (i * 256 + wbase) * 8;
            gl_lds16(Ah + asrc, ah_t + dst);
            gl_lds16(Al + asrc, al_t + dst);
            gl_lds16(Wh + bsrc, bh_t + dst);
            gl_lds16(Wl + bsrc, bl_t + dst);
        }
        __syncthreads();
        s16x8 fah[4], fal[4], fbh[4], fbl[4];
#pragma unroll
        for (int mf = 0; mf < 4; ++mf) {
            int row = wr * 64 + mf * 16 + lc;
            int off = row * 64 + ((lq * 16) ^ ((row & 3) << 4));
            fah[mf] = *(const s16x8*)((const char*)ah_t + off);
            fal[mf] = *(const s16x8*)((const char*)al_t + off);
        }
#pragma unroll
        for (int nf = 0; nf < 4; ++nf) {
            int row = wc * 64 + nf * 16 + lc;
            int off = row * 64 + ((lq * 16) ^ ((row & 3) << 4));
            fbh[nf] = *(const s16x8*)((const char*)bh_t + off);
            fbl[nf] = *(const s16x8*)((const char*)bl_t + off);
        }
#pragma unroll
        for (int mf = 0; mf < 4; ++mf)
#pragma unroll
            for (int nf = 0; nf < 4; ++nf) {
                acc[mf][nf] = mfma_bf16(fah[mf], fbh[nf], acc[mf][nf]);
                acc[mf][nf] = mfma_bf16(fah[mf], fbl[nf], acc[mf][nf]);
                acc[mf][nf] = mfma_bf16(fal[mf], fbh[nf], acc[mf][nf]);
            }
    }
#pragma unroll
    for (int mf = 0; mf < 4; ++mf)
#pragma unroll
        for (int nf = 0; nf < 4; ++nf)
#pragma unroll
            for (int r = 0; r < 4; ++r) {
                int grow = m0 + wr * 64 + mf * 16 + lq * 4 + r;
                int gcol = n0 + wc * 64 + nf * 16 + lc;
                out[(size_t)grow * 512 + gcol] = acc[mf][nf][r] * seq_mask[grow];
            }
}

// ---------------------------------------------------------------------------
extern "C" void kernel_launch(void* const* d_in, const int* in_sizes, int n_in,
                              void* d_out, int out_size, void* d_ws, size_t ws_size,
                              hipStream_t stream) {
    const float* x         = (const float*)d_in[0];
    const float* timev     = (const float*)d_in[1];
    const float* attn_bias = (const float*)d_in[2];
    const float* seq_mask  = (const float*)d_in[3];
    const float* gamma     = (const float*)d_in[4];
    const float* w_time    = (const float*)d_in[5];
    const float* b_time    = (const float*)d_in[6];
    const float* w_q       = (const float*)d_in[7];
    const float* w_kv      = (const float*)d_in[8];
    const float* w_out     = (const float*)d_in[9];
    float* out = (float*)d_out;

    char* ws = (char*)d_ws;
    size_t off = 0;
    auto alloc = [&](size_t bytes) {
        char* p = ws + off;
        off += (bytes + 255) & ~(size_t)255;
        return p;
    };
    float*          tc   = (float*)alloc(2048 * 4);
    unsigned short* wq   = (unsigned short*)alloc(262144 * 2);
    unsigned short* wkv  = (unsigned short*)alloc(524288 * 2);
    unsigned short* wo_h = (unsigned short*)alloc(262144 * 2);
    unsigned short* wo_l = (unsigned short*)alloc(262144 * 2);
    unsigned short* xbf  = (unsigned short*)alloc(2097152 * 2);
    unsigned short* xnbf = (unsigned short*)alloc(2097152 * 2);
    unsigned short* qb   = (unsigned short*)alloc(2097152 * 2);
    unsigned short* kb   = (unsigned short*)alloc(2097152 * 2);
    unsigned short* vtb  = (unsigned short*)alloc(2097152 * 2);
    unsigned short* ahh  = (unsigned short*)alloc(2097152 * 2);
    unsigned short* all_ = (unsigned short*)alloc(2097152 * 2);
    float*          po   = (float*)alloc((size_t)2 * 16 * 2048 * 64 * 4);  // 16.8MB
    float*          ml   = (float*)alloc((size_t)2 * 16 * 2048 * 2 * 4);   // 0.5MB

    k_prep<<<4096, 256, 0, stream>>>(w_q, w_kv, w_out, wq, wkv, wo_h, wo_l);
    k_time<<<512, 256, 0, stream>>>(timev, w_time, b_time, tc);
    k_lnfilm<<<4096, 256, 0, stream>>>(x, gamma, seq_mask, tc, xbf, xnbf);
    k_gemm<0><<<dim3(32, 4), 256, 0, stream>>>(xnbf, wq, qb, nullptr);
    k_gemm<1><<<dim3(32, 8), 256, 0, stream>>>(xbf, wkv, kb, vtb);
    k_attn<<<1024, 256, 0, stream>>>(qb, kb, vtb, attn_bias, seq_mask, po, ml);
    k_comb<<<512, 256, 0, stream>>>(po, ml, ahh, all_);
    k_gemm_out<<<dim3(32, 4), 256, 0, stream>>>(ahh, all_, wo_h, wo_l, seq_mask, out);
}

// Round 11
// 145.434 us; speedup vs baseline: 3.1077x; 1.1175x over previous
//
#include <hip/hip_runtime.h>
#include <stdint.h>

// ---------------------------------------------------------------------------
// TimeCondAttention on MI355X (gfx950)
// B=2, N=2048, DIM=512, H=8, DH=64, TIME_DIM=512
// R11: bias DRAM granularity 64B -> 256B (the invariant none of R1-R10 changed):
//   - bias load: lane -> (row=lane>>4, chunk=lane&15): 4x256B contiguous
//     segments per instruction (was 16x64B at 8KB stride)
//   - redistribute to MFMA lane layout via per-wave LDS scratch (stride 272B,
//     minimal bank touches; reuses P region, disjoint lifetimes)
//   - no key-split (drop k_comb/po/ml); grid 512; LDS 49KB -> 3 blocks/CU
//   - km-first vm order -> all compiler waits counted, never draining
//   - numerics identical to R10 (passed 1.22e-4)
// ---------------------------------------------------------------------------

using s16x8 = __attribute__((ext_vector_type(8))) short;
using f32x4 = __attribute__((ext_vector_type(4))) float;
using u16x4 = __attribute__((ext_vector_type(4))) unsigned short;
using u32x2 = __attribute__((ext_vector_type(2))) unsigned int;

#define EPSV 1e-5f
#define NEGV 1e6f
#define L2E  1.44269504088896341f
// q-projection scale: 0.125 * log2(e)
#define QSCL 0.18033688011112043f

__device__ __forceinline__ unsigned short f2bf(float f) {
    unsigned int u = __float_as_uint(f);
    u += 0x7FFFu + ((u >> 16) & 1u);   // RNE (inputs finite)
    return (unsigned short)(u >> 16);
}
__device__ __forceinline__ float bf2f(unsigned short s) {
    return __uint_as_float((unsigned int)s << 16);
}

__device__ __forceinline__ void gl_lds16(const void* g, void* l) {
    __builtin_amdgcn_global_load_lds((const __attribute__((address_space(1))) void*)g,
                                     (__attribute__((address_space(3))) void*)l, 16, 0, 0);
}

__device__ __forceinline__ f32x4 mfma_bf16(s16x8 a, s16x8 b, f32x4 c) {
    return __builtin_amdgcn_mfma_f32_16x16x32_bf16(a, b, c, 0, 0, 0);
}

// ---------------- K0: weight conversion (w_q, w_kv bf16; w_out hi/lo split) --
__global__ void k_prep(const float* __restrict__ w_q, const float* __restrict__ w_kv,
                       const float* __restrict__ w_out,
                       unsigned short* __restrict__ wq, unsigned short* __restrict__ wkv,
                       unsigned short* __restrict__ wo_h, unsigned short* __restrict__ wo_l) {
    int idx = blockIdx.x * 256 + threadIdx.x;         // total 1,048,576 exactly
    if (idx < 262144) {
        wq[idx] = f2bf(w_q[idx]);
    } else if (idx < 786432) {
        int i = idx - 262144;
        wkv[i] = f2bf(w_kv[i]);
    } else {
        int i = idx - 786432;
        float v = w_out[i];
        unsigned short h = f2bf(v);
        wo_h[i] = h;
        wo_l[i] = f2bf(v - bf2f(h));
    }
}

// ---------------- K1: t = silu(time) @ w_time.T + b_time  ([2][1024] f32) ----
__global__ void k_time(const float* __restrict__ timev, const float* __restrict__ w_time,
                       const float* __restrict__ b_time, float* __restrict__ tc) {
    int wid = threadIdx.x >> 6, lane = threadIdx.x & 63;
    int b = blockIdx.x >> 8;
    int j = (blockIdx.x & 255) * 4 + wid;             // 0..1023
    const float* tv = timev + b * 512;
    const float* wr = w_time + (size_t)j * 512;
    float acc = 0.f;
#pragma unroll
    for (int i = 0; i < 8; ++i) {
        int k = i * 64 + lane;
        float t = tv[k];
        float s = t / (1.f + __expf(-t));             // silu
        acc += s * wr[k];
    }
#pragma unroll
    for (int m = 32; m >= 1; m >>= 1) acc += __shfl_xor(acc, m);
    if (lane == 0) tc[b * 1024 + j] = acc + b_time[j];
}

// ---------------- K2: LayerNorm + FiLM + seq_mask -> xn(bf16); x -> bf16 -----
__global__ void k_lnfilm(const float* __restrict__ x, const float* __restrict__ gamma,
                         const float* __restrict__ seq_mask, const float* __restrict__ tc,
                         unsigned short* __restrict__ xbf, unsigned short* __restrict__ xnbf) {
    int row = blockIdx.x;                             // b*2048 + n
    int b = row >> 11;
    int tid = threadIdx.x, wid = tid >> 6, lane = tid & 63;
    float2 xv = *(const float2*)(x + (size_t)row * 512 + tid * 2);
    float s = xv.x + xv.y;
    float sq = xv.x * xv.x + xv.y * xv.y;
#pragma unroll
    for (int m = 32; m >= 1; m >>= 1) { s += __shfl_xor(s, m); sq += __shfl_xor(sq, m); }
    __shared__ float red[8];
    if (lane == 0) { red[wid] = s; red[wid + 4] = sq; }
    __syncthreads();
    float ts = red[0] + red[1] + red[2] + red[3];
    float tq = red[4] + red[5] + red[6] + red[7];
    float mu = ts * (1.f / 512.f);
    float var = tq * (1.f / 512.f) - mu * mu;
    float rs = rsqrtf(var + EPSV);
    float qm = seq_mask[row];
    int j = tid * 2;
    const float* scb = tc + b * 1024;
    float o0 = ((xv.x - mu) * rs * gamma[j])     * (scb[j] + 1.f)     + scb[j + 512];
    float o1 = ((xv.y - mu) * rs * gamma[j + 1]) * (scb[j + 1] + 1.f) + scb[j + 513];
    size_t base = (size_t)row * 512 + j;
    xnbf[base]     = f2bf(o0 * qm);
    xnbf[base + 1] = f2bf(o1 * qm);
    xbf[base]      = f2bf(xv.x);
    xbf[base + 1]  = f2bf(xv.y);
}

// ---------------- K3: bf16 GEMM C = A[M,512] * W[Nout,512]^T, scatter epi ----
// EPI 0: q-proj (scale 0.125*log2e, [b,h,n,d]); EPI 1: kv (k: [b,h,n,d], v: [b,h,d,n])
template<int EPI>
__launch_bounds__(256)
__global__ void k_gemm(const unsigned short* __restrict__ A, const unsigned short* __restrict__ W,
                       unsigned short* __restrict__ o0, unsigned short* __restrict__ o1) {
    __shared__ unsigned short a_t[128 * 64];
    __shared__ unsigned short b_t[128 * 64];
    int tid = threadIdx.x, lane = tid & 63, wid = tid >> 6;
    int lc = lane & 15, lq = lane >> 4;
    int wr = wid >> 1, wc = wid & 1;
    int m0 = blockIdx.x * 128, n0 = blockIdx.y * 128;
    f32x4 acc[4][4];
#pragma unroll
    for (int i = 0; i < 4; ++i)
#pragma unroll
        for (int jn = 0; jn < 4; ++jn)
#pragma unroll
            for (int e = 0; e < 4; ++e) acc[i][jn][e] = 0.f;
    const unsigned short* Ab = A + (size_t)m0 * 512;
    const unsigned short* Wb = W + (size_t)n0 * 512;
    int wbase = wid * 64;
    for (int kt = 0; kt < 8; ++kt) {
        __syncthreads();
#pragma unroll
        for (int i = 0; i < 4; ++i) {
            int p = i * 256 + wbase + lane;
            int row = p >> 3, ls = (p & 7) ^ (row & 7);
            gl_lds16(Ab + (size_t)row * 512 + kt * 64 + ls * 8, a_t + (i * 256 + wbase) * 8);
            gl_lds16(Wb + (size_t)row * 512 + kt * 64 + ls * 8, b_t + (i * 256 + wbase) * 8);
        }
        __syncthreads();
        s16x8 af[4][2], bw[4][2];
        const char* ab = (const char*)a_t;
        const char* bb = (const char*)b_t;
#pragma unroll
        for (int mf = 0; mf < 4; ++mf) {
            int row = wr * 64 + mf * 16 + lc;
            int key = (row & 7) << 4;
            af[mf][0] = *(const s16x8*)(ab + row * 128 + ((lq * 16) ^ key));
            af[mf][1] = *(const s16x8*)(ab + row * 128 + ((64 + lq * 16) ^ key));
        }
#pragma unroll
        for (int nf = 0; nf < 4; ++nf) {
            int row = wc * 64 + nf * 16 + lc;
            int key = (row & 7) << 4;
            bw[nf][0] = *(const s16x8*)(bb + row * 128 + ((lq * 16) ^ key));
            bw[nf][1] = *(const s16x8*)(bb + row * 128 + ((64 + lq * 16) ^ key));
        }
#pragma unroll
        for (int mf = 0; mf < 4; ++mf)
#pragma unroll
            for (int nf = 0; nf < 4; ++nf) {
                acc[mf][nf] = mfma_bf16(af[mf][0], bw[nf][0], acc[mf][nf]);
                acc[mf][nf] = mfma_bf16(af[mf][1], bw[nf][1], acc[mf][nf]);
            }
    }
#pragma unroll
    for (int mf = 0; mf < 4; ++mf)
#pragma unroll
        for (int nf = 0; nf < 4; ++nf) {
            int grow0 = m0 + wr * 64 + mf * 16 + lq * 4;
            int gcol = n0 + wc * 64 + nf * 16 + lc;
            int b = grow0 >> 11, nb = grow0 & 2047;
            if (EPI == 0) {
                int h = gcol >> 6, d = gcol & 63;
#pragma unroll
                for (int r = 0; r < 4; ++r)
                    o0[((size_t)((b * 8 + h) * 2048 + nb + r)) * 64 + d] =
                        f2bf(acc[mf][nf][r] * QSCL);
            } else if (gcol < 512) {
                int h = gcol >> 6, d = gcol & 63;
#pragma unroll
                for (int r = 0; r < 4; ++r)
                    o0[((size_t)((b * 8 + h) * 2048 + nb + r)) * 64 + d] = f2bf(acc[mf][nf][r]);
            } else {
                int jj = gcol & 511;
                int h = jj >> 6, d = jj & 63;
                u16x4 vv;
#pragma unroll
                for (int r = 0; r < 4; ++r) vv[r] = f2bf(acc[mf][nf][r]);
                *(u16x4*)(o1 + ((size_t)((b * 8 + h) * 64 + d)) * 2048 + nb) = vv;
            }
        }
}

// ---------------- K4: flash attention, 256B-granular bias via LDS exchange ---
__launch_bounds__(256)
__global__ void k_attn(const unsigned short* __restrict__ qg, const unsigned short* __restrict__ kg,
                       const unsigned short* __restrict__ vt, const float* __restrict__ bias,
                       const float* __restrict__ seq_mask,
                       unsigned short* __restrict__ ah, unsigned short* __restrict__ al) {
    __shared__ unsigned short k_ring[2][64 * 64];        // [key][d] swz8, 8KB/slot
    __shared__ unsigned short v_ring[2][64 * 64];        // [d][key] swz8, 8KB/slot
    __shared__ __align__(16) char scr[4][4352];          // per-wave bias/P scratch

    int tid = threadIdx.x, lane = tid & 63, w = tid >> 6;
    int lc = lane & 15, lq = lane >> 4;

    // XCD mapping: 512 blocks; XCD c hosts bh {2c,2c+1} (K/V L2-resident)
    int lin = blockIdx.x;
    int vid = (lin & 7) * 64 + (lin >> 3);
    int bh = vid >> 5;
    int q0 = (vid & 31) * 64 + w * 16;
    int b = bh >> 3, h = bh & 7;

    const unsigned short* qbase = qg + ((size_t)bh * 2048 + q0) * 64;
    s16x8 aq0 = *(const s16x8*)(qbase + lc * 64 + lq * 8);
    s16x8 aq1 = *(const s16x8*)(qbase + lc * 64 + 32 + lq * 8);

    const unsigned short* kb = kg + (size_t)bh * 2048 * 64;
    const unsigned short* vt0 = vt + (size_t)bh * 64 * 2048;
    const float* bqb = bias + ((size_t)bh * 2048 + q0) * 2048;   // wave's 16 rows
    const float* sk = seq_mask + b * 2048;
    const float NEG2 = NEGV * L2E;
    float qm_ = seq_mask[b * 2048 + q0 + lc];

    char* scw = &scr[w][0];
    int swz = (lc & 7) << 4;
    int brow = lane >> 4, bchk = lane & 15;              // bias load mapping

    float mst = -1e30f, lst = 0.f;
    f32x4 acc[4];
#pragma unroll
    for (int df = 0; df < 4; ++df)
#pragma unroll
        for (int e = 0; e < 4; ++e) acc[df][e] = 0.f;

    auto issue_k = [&](int tile, int slot) {
#pragma unroll
        for (int i = 0; i < 2; ++i) {
            int off = w * 2048 + i * 1024 + lane * 16;
            int row = off >> 7;
            int cc = ((off >> 4) & 7) ^ (row & 7);
            gl_lds16(kb + ((size_t)tile * 64 + row) * 64 + cc * 8,
                     (char*)k_ring[slot] + w * 2048 + i * 1024);
        }
    };
    auto issue_vt = [&](int tile, int slot) {
#pragma unroll
        for (int i = 0; i < 2; ++i) {
            int off = w * 2048 + i * 1024 + lane * 16;
            int row = off >> 7;
            int cc = ((off >> 4) & 7) ^ (row & 7);
            gl_lds16(vt0 + (size_t)row * 2048 + tile * 64 + cc * 8,
                     (char*)v_ring[slot] + w * 2048 + i * 1024);
        }
    };
    // 256B-granular bias load: instr i = rows 4i..4i+3, lane -> (row, chunk)
    auto bias_ld = [&](int kt, f32x4 (&dst)[4]) {
#pragma unroll
        for (int i = 0; i < 4; ++i)
            dst[i] = *(const f32x4*)(bqb + (size_t)(4 * i + brow) * 2048 + kt * 64 + bchk * 4);
    };

    f32x4 brA[4], brB[4];

    // ---- prologue: KV(0)->slot0; bias(0)->brA; full drain; barrier ----
    issue_k(0, 0);
    issue_vt(0, 0);
    __builtin_amdgcn_sched_barrier(0);
    bias_ld(0, brA);
    __builtin_amdgcn_sched_barrier(0);
    asm volatile("s_waitcnt vmcnt(0)");
    __builtin_amdgcn_s_barrier();
    __builtin_amdgcn_sched_barrier(0);

    auto iter = [&](int kt, int par, f32x4 (&cur)[4], f32x4 (&nxt)[4]) {
        const int slot_nxt = par ^ 1;

        // ---- phase 0: km FIRST (oldest this iter -> counted waits only) ----
        f32x4 km[4];
#pragma unroll
        for (int nf = 0; nf < 4; ++nf)
            km[nf] = *(const f32x4*)(sk + kt * 64 + nf * 16 + lq * 4);
        __builtin_amdgcn_sched_barrier(0);

        // ---- phase A: prefetch KV(kt+1); then bias(kt+1) (newest 4) ----
        {
            int tk = (kt + 1 < 32) ? kt + 1 : 31;
            issue_k(tk, slot_nxt);
            issue_vt(tk, slot_nxt);
            __builtin_amdgcn_sched_barrier(0);
            bias_ld(tk, nxt);
        }
        __builtin_amdgcn_sched_barrier(0);

        // ---- phase B: S^T = K Q^T (log2-domain Q) ----
        const char* klds = (const char*)k_ring[par];
        f32x4 sv[4];
        __builtin_amdgcn_s_setprio(1);
#pragma unroll
        for (int nf = 0; nf < 4; ++nf) {
            int row = nf * 16 + lc;
            s16x8 b0 = *(const s16x8*)(klds + row * 128 + ((lq * 16) ^ swz));
            s16x8 b1 = *(const s16x8*)(klds + row * 128 + ((64 + lq * 16) ^ swz));
            f32x4 z;
            z[0] = 0.f; z[1] = 0.f; z[2] = 0.f; z[3] = 0.f;
            z = mfma_bf16(b0, aq0, z);
            z = mfma_bf16(b1, aq1, z);
            sv[nf] = z;
        }
        __builtin_amdgcn_s_setprio(0);

        // ---- phase C: redistribute bias cur regs -> wave scratch -> lanes ----
        //      write: lane=(brow,bchk), row 4i+brow, stride 272B (min bank touches)
#pragma unroll
        for (int i = 0; i < 4; ++i)
            *(f32x4*)(scw + (4 * i + brow) * 272 + bchk * 16) = cur[i];
        __builtin_amdgcn_sched_barrier(0);
        asm volatile("s_waitcnt lgkmcnt(0)");
        __builtin_amdgcn_sched_barrier(0);      // rule #18
        f32x4 bv[4];
#pragma unroll
        for (int nf = 0; nf < 4; ++nf)
            bv[nf] = *(const f32x4*)(scw + lc * 272 + (nf * 4 + lq) * 16);

        // ---- phase D: bias*log2e + mask penalty (exact 0 when unmasked) ----
#pragma unroll
        for (int nf = 0; nf < 4; ++nf) {
#pragma unroll
            for (int e = 0; e < 4; ++e) {
                float pen = __builtin_fmaf(km[nf][e], qm_, -1.0f) * NEG2;
                sv[nf][e] = __builtin_fmaf(bv[nf][e], L2E, sv[nf][e]) + pen;
            }
        }

        // ---- phase E: online softmax, defer-max, cvt_pk P store ----
        f32x4 m4 = sv[0];
#pragma unroll
        for (int nf = 1; nf < 4; ++nf)
#pragma unroll
            for (int e = 0; e < 4; ++e) m4[e] = fmaxf(m4[e], sv[nf][e]);
        float mx = fmaxf(fmaxf(m4[0], m4[1]), fmaxf(m4[2], m4[3]));
        mx = fmaxf(mx, __shfl_xor(mx, 16));
        mx = fmaxf(mx, __shfl_xor(mx, 32));
        if (!__all(mx <= mst + 11.54f)) {
            float mn = fmaxf(mst, mx);
            float scl = __builtin_amdgcn_exp2f(mst - mn);
            lst *= scl;
#pragma unroll
            for (int df = 0; df < 4; ++df)
#pragma unroll
                for (int e = 0; e < 4; ++e) acc[df][e] *= scl;
            mst = mn;
        }
        float rsum = 0.f;
#pragma unroll
        for (int nf = 0; nf < 4; ++nf) {
            f32x4 p;
#pragma unroll
            for (int e = 0; e < 4; ++e) {
                p[e] = __builtin_amdgcn_exp2f(sv[nf][e] - mst);
                rsum += p[e];
            }
            unsigned int pk01, pk23;
            asm("v_cvt_pk_bf16_f32 %0, %1, %2" : "=v"(pk01) : "v"(p[0]), "v"(p[1]));
            asm("v_cvt_pk_bf16_f32 %0, %1, %2" : "=v"(pk23) : "v"(p[2]), "v"(p[3]));
            u32x2 pkv;
            pkv[0] = pk01; pkv[1] = pk23;
            *(u32x2*)(scw + lc * 128 + ((nf * 32 + lq * 8) ^ swz)) = pkv;
        }
        rsum += __shfl_xor(rsum, 16);
        rsum += __shfl_xor(rsum, 32);
        lst += rsum;

        __builtin_amdgcn_sched_barrier(0);
        asm volatile("s_waitcnt lgkmcnt(0)");   // P visible (wave-local)
        __builtin_amdgcn_sched_barrier(0);      // rule #18

        // ---- phase F: O^T += V^T P^T ----
        s16x8 ap0 = *(const s16x8*)(scw + lc * 128 + ((lq * 16) ^ swz));
        s16x8 ap1 = *(const s16x8*)(scw + lc * 128 + ((64 + lq * 16) ^ swz));
        const char* vlds = (const char*)v_ring[par];
        __builtin_amdgcn_s_setprio(1);
#pragma unroll
        for (int df = 0; df < 4; ++df) {
            int row = df * 16 + lc;
            int key = (row & 7) << 4;
            s16x8 av0 = *(const s16x8*)(vlds + row * 128 + ((lq * 16) ^ key));
            s16x8 av1 = *(const s16x8*)(vlds + row * 128 + ((64 + lq * 16) ^ key));
            acc[df] = mfma_bf16(av0, ap0, acc[df]);
            acc[df] = mfma_bf16(av1, ap1, acc[df]);
        }
        __builtin_amdgcn_s_setprio(0);

        // ---- tail: km+KV(kt+1) drained; bias(kt+1) (newest 4) flies on ----
        __builtin_amdgcn_sched_barrier(0);
        asm volatile("s_waitcnt vmcnt(4) lgkmcnt(0)");
        __builtin_amdgcn_s_barrier();
        __builtin_amdgcn_sched_barrier(0);
    };

    for (int t = 0; t < 16; ++t) {
        iter(2 * t,     0, brA, brB);
        iter(2 * t + 1, 1, brB, brA);
    }
    asm volatile("s_waitcnt vmcnt(0)");   // retire dangling clamped prefetches

    // ---- epilogue: O[q=lc][d], hi/lo bf16 split for precise out-proj ----
    float inv = 1.f / lst;
    size_t rowb = ((size_t)(b * 2048 + q0 + lc)) * 512 + h * 64;
#pragma unroll
    for (int df = 0; df < 4; ++df) {
        u16x4 hi, lo;
#pragma unroll
        for (int r = 0; r < 4; ++r) {
            float o = acc[df][r] * inv;
            unsigned short hb = f2bf(o);
            hi[r] = hb;
            lo[r] = f2bf(o - bf2f(hb));
        }
        *(u16x4*)(ah + rowb + df * 16 + lq * 4) = hi;
        *(u16x4*)(al + rowb + df * 16 + lq * 4) = lo;
    }
}

// ---------------- K5: out = (Ah+Al)(Wh+Wl)^T * seq_mask  (3-term split) -----
__launch_bounds__(256)
__global__ void k_gemm_out(const unsigned short* __restrict__ Ah, const unsigned short* __restrict__ Al,
                           const unsigned short* __restrict__ Wh, const unsigned short* __restrict__ Wl,
                           const float* __restrict__ seq_mask, float* __restrict__ out) {
    __shared__ unsigned short ah_t[128 * 32], al_t[128 * 32], bh_t[128 * 32], bl_t[128 * 32];
    int tid = threadIdx.x, lane = tid & 63, wid = tid >> 6;
    int lc = lane & 15, lq = lane >> 4;
    int wr = wid >> 1, wc = wid & 1;
    int m0 = blockIdx.x * 128, n0 = blockIdx.y * 128;
    f32x4 acc[4][4];
#pragma unroll
    for (int i = 0; i < 4; ++i)
#pragma unroll
        for (int jn = 0; jn < 4; ++jn)
#pragma unroll
            for (int e = 0; e < 4; ++e) acc[i][jn][e] = 0.f;
    int wbase = wid * 64;
    for (int kt = 0; kt < 16; ++kt) {
        __syncthreads();
#pragma unroll
        for (int i = 0; i < 2; ++i) {
            int p = i * 256 + wbase + lane;
            int row = p >> 2, ls = (p & 3) ^ (row & 3);
            size_t asrc = (size_t)(m0 + row) * 512 + kt * 32 + ls * 8;
            size_t bsrc = (size_t)(n0 + row) * 512 + kt * 32 + ls * 8;
            int dst = (i * 256 + wbase) * 8;
            gl_lds16(Ah + asrc, ah_t + dst);
            gl_lds16(Al + asrc, al_t + dst);
            gl_lds16(Wh + bsrc, bh_t + dst);
            gl_lds16(Wl + bsrc, bl_t + dst);
        }
        __syncthreads();
        s16x8 fah[4], fal[4], fbh[4], fbl[4];
#pragma unroll
        for (int mf = 0; mf < 4; ++mf) {
            int row = wr * 64 + mf * 16 + lc;
            int off = row * 64 + ((lq * 16) ^ ((row & 3) << 4));
            fah[mf] = *(const s16x8*)((const char*)ah_t + off);
            fal[mf] = *(const s16x8*)((const char*)al_t + off);
        }
#pragma unroll
        for (int nf = 0; nf < 4; ++nf) {
            int row = wc * 64 + nf * 16 + lc;
            int off = row * 64 + ((lq * 16) ^ ((row & 3) << 4));
            fbh[nf] = *(const s16x8*)((const char*)bh_t + off);
            fbl[nf] = *(const s16x8*)((const char*)bl_t + off);
        }
#pragma unroll
        for (int mf = 0; mf < 4; ++mf)
#pragma unroll
            for (int nf = 0; nf < 4; ++nf) {
                acc[mf][nf] = mfma_bf16(fah[mf], fbh[nf], acc[mf][nf]);
                acc[mf][nf] = mfma_bf16(fah[mf], fbl[nf], acc[mf][nf]);
                acc[mf][nf] = mfma_bf16(fal[mf], fbh[nf], acc[mf][nf]);
            }
    }
#pragma unroll
    for (int mf = 0; mf < 4; ++mf)
#pragma unroll
        for (int nf = 0; nf < 4; ++nf)
#pragma unroll
            for (int r = 0; r < 4; ++r) {
                int grow = m0 + wr * 64 + mf * 16 + lq * 4 + r;
                int gcol = n0 + wc * 64 + nf * 16 + lc;
                out[(size_t)grow * 512 + gcol] = acc[mf][nf][r] * seq_mask[grow];
            }
}

// ---------------------------------------------------------------------------
extern "C" void kernel_launch(void* const* d_in, const int* in_sizes, int n_in,
                              void* d_out, int out_size, void* d_ws, size_t ws_size,
                              hipStream_t stream) {
    const float* x         = (const float*)d_in[0];
    const float* timev     = (const float*)d_in[1];
    const float* attn_bias = (const float*)d_in[2];
    const float* seq_mask  = (const float*)d_in[3];
    const float* gamma     = (const float*)d_in[4];
    const float* w_time    = (const float*)d_in[5];
    const float* b_time    = (const float*)d_in[6];
    const float* w_q       = (const float*)d_in[7];
    const float* w_kv      = (const float*)d_in[8];
    const float* w_out     = (const float*)d_in[9];
    float* out = (float*)d_out;

    char* ws = (char*)d_ws;
    size_t off = 0;
    auto alloc = [&](size_t bytes) {
        char* p = ws + off;
        off += (bytes + 255) & ~(size_t)255;
        return p;
    };
    float*          tc   = (float*)alloc(2048 * 4);
    unsigned short* wq   = (unsigned short*)alloc(262144 * 2);
    unsigned short* wkv  = (unsigned short*)alloc(524288 * 2);
    unsigned short* wo_h = (unsigned short*)alloc(262144 * 2);
    unsigned short* wo_l = (unsigned short*)alloc(262144 * 2);
    unsigned short* xbf  = (unsigned short*)alloc(2097152 * 2);
    unsigned short* xnbf = (unsigned short*)alloc(2097152 * 2);
    unsigned short* qb   = (unsigned short*)alloc(2097152 * 2);
    unsigned short* kb   = (unsigned short*)alloc(2097152 * 2);
    unsigned short* vtb  = (unsigned short*)alloc(2097152 * 2);
    unsigned short* ahh  = (unsigned short*)alloc(2097152 * 2);
    unsigned short* all_ = (unsigned short*)alloc(2097152 * 2);

    k_prep<<<4096, 256, 0, stream>>>(w_q, w_kv, w_out, wq, wkv, wo_h, wo_l);
    k_time<<<512, 256, 0, stream>>>(timev, w_time, b_time, tc);
    k_lnfilm<<<4096, 256, 0, stream>>>(x, gamma, seq_mask, tc, xbf, xnbf);
    k_gemm<0><<<dim3(32, 4), 256, 0, stream>>>(xnbf, wq, qb, nullptr);
    k_gemm<1><<<dim3(32, 8), 256, 0, stream>>>(xbf, wkv, kb, vtb);
    k_attn<<<512, 256, 0, stream>>>(qb, kb, vtb, attn_bias, seq_mask, ahh, all_);
    k_gemm_out<<<dim3(32, 4), 256, 0, stream>>>(ahh, all_, wo_h, wo_l, seq_mask, out);
}

// Round 12
// 141.953 us; speedup vs baseline: 3.1839x; 1.0245x over previous
//
#include <hip/hip_runtime.h>
#include <stdint.h>

// ---------------------------------------------------------------------------
// TimeCondAttention on MI355X (gfx950)
// B=2, N=2048, DIM=512, H=8, DH=64, TIME_DIM=512
// R12: bias staged straight to LDS via global_load_lds (R11 kept the 256B
//      source granularity but round-tripped through registers + LDS exchange):
//   - issue_b: 4x1KB gl_lds16/wave/tile, 2-slot ring; source pre-swizzled
//     (chunk ^= row&7) so linear dest reads back conflict-free (rule #21)
//   - phase-C reg->LDS exchange deleted; bias reg rings deleted (-32 VGPR)
//   - phase D: s_waitcnt vmcnt(8) pins bias_cur+km retired; KV_next+bias_next
//     fly across the barrier (counted, never draining)
//   - LDS 72KB -> 2 blocks/CU; numerics identical to R11 (passed 1.22e-4)
// ---------------------------------------------------------------------------

using s16x8 = __attribute__((ext_vector_type(8))) short;
using f32x4 = __attribute__((ext_vector_type(4))) float;
using u16x4 = __attribute__((ext_vector_type(4))) unsigned short;
using u32x2 = __attribute__((ext_vector_type(2))) unsigned int;

#define EPSV 1e-5f
#define NEGV 1e6f
#define L2E  1.44269504088896341f
// q-projection scale: 0.125 * log2(e)
#define QSCL 0.18033688011112043f

__device__ __forceinline__ unsigned short f2bf(float f) {
    unsigned int u = __float_as_uint(f);
    u += 0x7FFFu + ((u >> 16) & 1u);   // RNE (inputs finite)
    return (unsigned short)(u >> 16);
}
__device__ __forceinline__ float bf2f(unsigned short s) {
    return __uint_as_float((unsigned int)s << 16);
}

__device__ __forceinline__ void gl_lds16(const void* g, void* l) {
    __builtin_amdgcn_global_load_lds((const __attribute__((address_space(1))) void*)g,
                                     (__attribute__((address_space(3))) void*)l, 16, 0, 0);
}

__device__ __forceinline__ f32x4 mfma_bf16(s16x8 a, s16x8 b, f32x4 c) {
    return __builtin_amdgcn_mfma_f32_16x16x32_bf16(a, b, c, 0, 0, 0);
}

// ---------------- K0: weight conversion (w_q, w_kv bf16; w_out hi/lo split) --
__global__ void k_prep(const float* __restrict__ w_q, const float* __restrict__ w_kv,
                       const float* __restrict__ w_out,
                       unsigned short* __restrict__ wq, unsigned short* __restrict__ wkv,
                       unsigned short* __restrict__ wo_h, unsigned short* __restrict__ wo_l) {
    int idx = blockIdx.x * 256 + threadIdx.x;         // total 1,048,576 exactly
    if (idx < 262144) {
        wq[idx] = f2bf(w_q[idx]);
    } else if (idx < 786432) {
        int i = idx - 262144;
        wkv[i] = f2bf(w_kv[i]);
    } else {
        int i = idx - 786432;
        float v = w_out[i];
        unsigned short h = f2bf(v);
        wo_h[i] = h;
        wo_l[i] = f2bf(v - bf2f(h));
    }
}

// ---------------- K1: t = silu(time) @ w_time.T + b_time  ([2][1024] f32) ----
__global__ void k_time(const float* __restrict__ timev, const float* __restrict__ w_time,
                       const float* __restrict__ b_time, float* __restrict__ tc) {
    int wid = threadIdx.x >> 6, lane = threadIdx.x & 63;
    int b = blockIdx.x >> 8;
    int j = (blockIdx.x & 255) * 4 + wid;             // 0..1023
    const float* tv = timev + b * 512;
    const float* wr = w_time + (size_t)j * 512;
    float acc = 0.f;
#pragma unroll
    for (int i = 0; i < 8; ++i) {
        int k = i * 64 + lane;
        float t = tv[k];
        float s = t / (1.f + __expf(-t));             // silu
        acc += s * wr[k];
    }
#pragma unroll
    for (int m = 32; m >= 1; m >>= 1) acc += __shfl_xor(acc, m);
    if (lane == 0) tc[b * 1024 + j] = acc + b_time[j];
}

// ---------------- K2: LayerNorm + FiLM + seq_mask -> xn(bf16); x -> bf16 -----
__global__ void k_lnfilm(const float* __restrict__ x, const float* __restrict__ gamma,
                         const float* __restrict__ seq_mask, const float* __restrict__ tc,
                         unsigned short* __restrict__ xbf, unsigned short* __restrict__ xnbf) {
    int row = blockIdx.x;                             // b*2048 + n
    int b = row >> 11;
    int tid = threadIdx.x, wid = tid >> 6, lane = tid & 63;
    float2 xv = *(const float2*)(x + (size_t)row * 512 + tid * 2);
    float s = xv.x + xv.y;
    float sq = xv.x * xv.x + xv.y * xv.y;
#pragma unroll
    for (int m = 32; m >= 1; m >>= 1) { s += __shfl_xor(s, m); sq += __shfl_xor(sq, m); }
    __shared__ float red[8];
    if (lane == 0) { red[wid] = s; red[wid + 4] = sq; }
    __syncthreads();
    float ts = red[0] + red[1] + red[2] + red[3];
    float tq = red[4] + red[5] + red[6] + red[7];
    float mu = ts * (1.f / 512.f);
    float var = tq * (1.f / 512.f) - mu * mu;
    float rs = rsqrtf(var + EPSV);
    float qm = seq_mask[row];
    int j = tid * 2;
    const float* scb = tc + b * 1024;
    float o0 = ((xv.x - mu) * rs * gamma[j])     * (scb[j] + 1.f)     + scb[j + 512];
    float o1 = ((xv.y - mu) * rs * gamma[j + 1]) * (scb[j + 1] + 1.f) + scb[j + 513];
    size_t base = (size_t)row * 512 + j;
    xnbf[base]     = f2bf(o0 * qm);
    xnbf[base + 1] = f2bf(o1 * qm);
    xbf[base]      = f2bf(xv.x);
    xbf[base + 1]  = f2bf(xv.y);
}

// ---------------- K3: bf16 GEMM C = A[M,512] * W[Nout,512]^T, scatter epi ----
// EPI 0: q-proj (scale 0.125*log2e, [b,h,n,d]); EPI 1: kv (k: [b,h,n,d], v: [b,h,d,n])
template<int EPI>
__launch_bounds__(256)
__global__ void k_gemm(const unsigned short* __restrict__ A, const unsigned short* __restrict__ W,
                       unsigned short* __restrict__ o0, unsigned short* __restrict__ o1) {
    __shared__ unsigned short a_t[128 * 64];
    __shared__ unsigned short b_t[128 * 64];
    int tid = threadIdx.x, lane = tid & 63, wid = tid >> 6;
    int lc = lane & 15, lq = lane >> 4;
    int wr = wid >> 1, wc = wid & 1;
    int m0 = blockIdx.x * 128, n0 = blockIdx.y * 128;
    f32x4 acc[4][4];
#pragma unroll
    for (int i = 0; i < 4; ++i)
#pragma unroll
        for (int jn = 0; jn < 4; ++jn)
#pragma unroll
            for (int e = 0; e < 4; ++e) acc[i][jn][e] = 0.f;
    const unsigned short* Ab = A + (size_t)m0 * 512;
    const unsigned short* Wb = W + (size_t)n0 * 512;
    int wbase = wid * 64;
    for (int kt = 0; kt < 8; ++kt) {
        __syncthreads();
#pragma unroll
        for (int i = 0; i < 4; ++i) {
            int p = i * 256 + wbase + lane;
            int row = p >> 3, ls = (p & 7) ^ (row & 7);
            gl_lds16(Ab + (size_t)row * 512 + kt * 64 + ls * 8, a_t + (i * 256 + wbase) * 8);
            gl_lds16(Wb + (size_t)row * 512 + kt * 64 + ls * 8, b_t + (i * 256 + wbase) * 8);
        }
        __syncthreads();
        s16x8 af[4][2], bw[4][2];
        const char* ab = (const char*)a_t;
        const char* bb = (const char*)b_t;
#pragma unroll
        for (int mf = 0; mf < 4; ++mf) {
            int row = wr * 64 + mf * 16 + lc;
            int key = (row & 7) << 4;
            af[mf][0] = *(const s16x8*)(ab + row * 128 + ((lq * 16) ^ key));
            af[mf][1] = *(const s16x8*)(ab + row * 128 + ((64 + lq * 16) ^ key));
        }
#pragma unroll
        for (int nf = 0; nf < 4; ++nf) {
            int row = wc * 64 + nf * 16 + lc;
            int key = (row & 7) << 4;
            bw[nf][0] = *(const s16x8*)(bb + row * 128 + ((lq * 16) ^ key));
            bw[nf][1] = *(const s16x8*)(bb + row * 128 + ((64 + lq * 16) ^ key));
        }
#pragma unroll
        for (int mf = 0; mf < 4; ++mf)
#pragma unroll
            for (int nf = 0; nf < 4; ++nf) {
                acc[mf][nf] = mfma_bf16(af[mf][0], bw[nf][0], acc[mf][nf]);
                acc[mf][nf] = mfma_bf16(af[mf][1], bw[nf][1], acc[mf][nf]);
            }
    }
#pragma unroll
    for (int mf = 0; mf < 4; ++mf)
#pragma unroll
        for (int nf = 0; nf < 4; ++nf) {
            int grow0 = m0 + wr * 64 + mf * 16 + lq * 4;
            int gcol = n0 + wc * 64 + nf * 16 + lc;
            int b = grow0 >> 11, nb = grow0 & 2047;
            if (EPI == 0) {
                int h = gcol >> 6, d = gcol & 63;
#pragma unroll
                for (int r = 0; r < 4; ++r)
                    o0[((size_t)((b * 8 + h) * 2048 + nb + r)) * 64 + d] =
                        f2bf(acc[mf][nf][r] * QSCL);
            } else if (gcol < 512) {
                int h = gcol >> 6, d = gcol & 63;
#pragma unroll
                for (int r = 0; r < 4; ++r)
                    o0[((size_t)((b * 8 + h) * 2048 + nb + r)) * 64 + d] = f2bf(acc[mf][nf][r]);
            } else {
                int jj = gcol & 511;
                int h = jj >> 6, d = jj & 63;
                u16x4 vv;
#pragma unroll
                for (int r = 0; r < 4; ++r) vv[r] = f2bf(acc[mf][nf][r]);
                *(u16x4*)(o1 + ((size_t)((b * 8 + h) * 64 + d)) * 2048 + nb) = vv;
            }
        }
}

// ---------------- K4: flash attention, bias gl_lds16 -> LDS (256B granular) --
__launch_bounds__(256)
__global__ void k_attn(const unsigned short* __restrict__ qg, const unsigned short* __restrict__ kg,
                       const unsigned short* __restrict__ vt, const float* __restrict__ bias,
                       const float* __restrict__ seq_mask,
                       unsigned short* __restrict__ ah, unsigned short* __restrict__ al) {
    __shared__ unsigned short k_ring[2][64 * 64];     // [key][d] swz8, 8KB/slot
    __shared__ unsigned short v_ring[2][64 * 64];     // [d][key] swz8, 8KB/slot
    __shared__ __align__(16) char b_ring[2][16384];   // bias [64 rows][256B], swz
    __shared__ __align__(16) char scr[4][2048];       // per-wave P scratch

    int tid = threadIdx.x, lane = tid & 63, w = tid >> 6;
    int lc = lane & 15, lq = lane >> 4;

    // XCD mapping: 512 blocks; XCD c hosts bh {2c,2c+1} (K/V L2-resident)
    int lin = blockIdx.x;
    int vid = (lin & 7) * 64 + (lin >> 3);
    int bh = vid >> 5;
    int q0 = (vid & 31) * 64 + w * 16;
    int b = bh >> 3, h = bh & 7;

    const unsigned short* qbase = qg + ((size_t)bh * 2048 + q0) * 64;
    s16x8 aq0 = *(const s16x8*)(qbase + lc * 64 + lq * 8);
    s16x8 aq1 = *(const s16x8*)(qbase + lc * 64 + 32 + lq * 8);

    const unsigned short* kb = kg + (size_t)bh * 2048 * 64;
    const unsigned short* vt0 = vt + (size_t)bh * 64 * 2048;
    const float* bqb = bias + ((size_t)bh * 2048 + q0) * 2048;   // wave's 16 rows
    const float* sk = seq_mask + b * 2048;
    const float NEG2 = NEGV * L2E;
    float qm_ = seq_mask[b * 2048 + q0 + lc];

    char* pw = &scr[w][0];
    int swz = (lc & 7) << 4;
    int brow = lane >> 4, bchk = lane & 15;            // bias load mapping

    float mst = -1e30f, lst = 0.f;
    f32x4 acc[4];
#pragma unroll
    for (int df = 0; df < 4; ++df)
#pragma unroll
        for (int e = 0; e < 4; ++e) acc[df][e] = 0.f;

    auto issue_k = [&](int tile, int slot) {
#pragma unroll
        for (int i = 0; i < 2; ++i) {
            int off = w * 2048 + i * 1024 + lane * 16;
            int row = off >> 7;
            int cc = ((off >> 4) & 7) ^ (row & 7);
            gl_lds16(kb + ((size_t)tile * 64 + row) * 64 + cc * 8,
                     (char*)k_ring[slot] + w * 2048 + i * 1024);
        }
    };
    auto issue_vt = [&](int tile, int slot) {
#pragma unroll
        for (int i = 0; i < 2; ++i) {
            int off = w * 2048 + i * 1024 + lane * 16;
            int row = off >> 7;
            int cc = ((off >> 4) & 7) ^ (row & 7);
            gl_lds16(vt0 + (size_t)row * 2048 + tile * 64 + cc * 8,
                     (char*)v_ring[slot] + w * 2048 + i * 1024);
        }
    };
    // bias: instr i = rows 4i..4i+3 of wave's 16; 4x256B contiguous segments.
    // Source chunk pre-swizzled (kc = pos ^ (row&7)) so LDS reads are ~2-way.
    auto issue_b = [&](int tile, int slot) {
#pragma unroll
        for (int i = 0; i < 4; ++i) {
            int row = i * 4 + brow;                    // wave-local 0..15
            int kc = bchk ^ (row & 7);                 // 16B chunk index
            gl_lds16(bqb + (size_t)row * 2048 + tile * 64 + kc * 4,
                     (char*)b_ring[slot] + w * 4096 + i * 1024);
        }
    };

    // ---- prologue: KV(0)+bias(0) -> slot0; drain; barrier ----
    issue_k(0, 0);
    issue_vt(0, 0);
    issue_b(0, 0);
    __builtin_amdgcn_sched_barrier(0);
    asm volatile("s_waitcnt vmcnt(0)");
    __builtin_amdgcn_s_barrier();
    __builtin_amdgcn_sched_barrier(0);

    auto iter = [&](int kt, int par) {
        const int slot_nxt = par ^ 1;

        // ---- phase 0: km FIRST (oldest this iter -> counted waits only) ----
        f32x4 km[4];
#pragma unroll
        for (int nf = 0; nf < 4; ++nf)
            km[nf] = *(const f32x4*)(sk + kt * 64 + nf * 16 + lq * 4);
        __builtin_amdgcn_sched_barrier(0);

        // ---- phase A: prefetch KV(kt+1) then bias(kt+1) (newest 4) ----
        {
            int tk = (kt + 1 < 32) ? kt + 1 : 31;
            issue_k(tk, slot_nxt);
            issue_vt(tk, slot_nxt);
            __builtin_amdgcn_sched_barrier(0);
            issue_b(tk, slot_nxt);
        }
        __builtin_amdgcn_sched_barrier(0);

        // ---- phase B: S^T = K Q^T (log2-domain Q) ----
        const char* klds = (const char*)k_ring[par];
        f32x4 sv[4];
        __builtin_amdgcn_s_setprio(1);
#pragma unroll
        for (int nf = 0; nf < 4; ++nf) {
            int row = nf * 16 + lc;
            s16x8 b0 = *(const s16x8*)(klds + row * 128 + ((lq * 16) ^ swz));
            s16x8 b1 = *(const s16x8*)(klds + row * 128 + ((64 + lq * 16) ^ swz));
            f32x4 z;
            z[0] = 0.f; z[1] = 0.f; z[2] = 0.f; z[3] = 0.f;
            z = mfma_bf16(b0, aq0, z);
            z = mfma_bf16(b1, aq1, z);
            sv[nf] = z;
        }
        __builtin_amdgcn_s_setprio(0);

        // ---- phase C: bias from LDS (bias_cur + km retired at vmcnt(8);
        //      KV_next + bias_next stay in flight) ----
        __builtin_amdgcn_sched_barrier(0);
        asm volatile("s_waitcnt vmcnt(8)");
        __builtin_amdgcn_sched_barrier(0);
        const char* bws = (const char*)b_ring[par] + w * 4096;
        f32x4 bv[4];
#pragma unroll
        for (int nf = 0; nf < 4; ++nf)
            bv[nf] = *(const f32x4*)(bws + lc * 256 + ((((nf << 2) + lq) ^ (lc & 7)) << 4));

        // ---- phase D: bias*log2e + mask penalty (exact 0 when unmasked) ----
#pragma unroll
        for (int nf = 0; nf < 4; ++nf) {
#pragma unroll
            for (int e = 0; e < 4; ++e) {
                float pen = __builtin_fmaf(km[nf][e], qm_, -1.0f) * NEG2;
                sv[nf][e] = __builtin_fmaf(bv[nf][e], L2E, sv[nf][e]) + pen;
            }
        }

        // ---- phase E: online softmax, defer-max, cvt_pk P store ----
        f32x4 m4 = sv[0];
#pragma unroll
        for (int nf = 1; nf < 4; ++nf)
#pragma unroll
            for (int e = 0; e < 4; ++e) m4[e] = fmaxf(m4[e], sv[nf][e]);
        float mx = fmaxf(fmaxf(m4[0], m4[1]), fmaxf(m4[2], m4[3]));
        mx = fmaxf(mx, __shfl_xor(mx, 16));
        mx = fmaxf(mx, __shfl_xor(mx, 32));
        if (!__all(mx <= mst + 11.54f)) {
            float mn = fmaxf(mst, mx);
            float scl = __builtin_amdgcn_exp2f(mst - mn);
            lst *= scl;
#pragma unroll
            for (int df = 0; df < 4; ++df)
#pragma unroll
                for (int e = 0; e < 4; ++e) acc[df][e] *= scl;
            mst = mn;
        }
        float rsum = 0.f;
#pragma unroll
        for (int nf = 0; nf < 4; ++nf) {
            f32x4 p;
#pragma unroll
            for (int e = 0; e < 4; ++e) {
                p[e] = __builtin_amdgcn_exp2f(sv[nf][e] - mst);
                rsum += p[e];
            }
            unsigned int pk01, pk23;
            asm("v_cvt_pk_bf16_f32 %0, %1, %2" : "=v"(pk01) : "v"(p[0]), "v"(p[1]));
            asm("v_cvt_pk_bf16_f32 %0, %1, %2" : "=v"(pk23) : "v"(p[2]), "v"(p[3]));
            u32x2 pkv;
            pkv[0] = pk01; pkv[1] = pk23;
            *(u32x2*)(pw + lc * 128 + ((nf * 32 + lq * 8) ^ swz)) = pkv;
        }
        rsum += __shfl_xor(rsum, 16);
        rsum += __shfl_xor(rsum, 32);
        lst += rsum;

        __builtin_amdgcn_sched_barrier(0);
        asm volatile("s_waitcnt lgkmcnt(0)");   // P visible (wave-local)
        __builtin_amdgcn_sched_barrier(0);      // rule #18

        // ---- phase F: O^T += V^T P^T ----
        s16x8 ap0 = *(const s16x8*)(pw + lc * 128 + ((lq * 16) ^ swz));
        s16x8 ap1 = *(const s16x8*)(pw + lc * 128 + ((64 + lq * 16) ^ swz));
        const char* vlds = (const char*)v_ring[par];
        __builtin_amdgcn_s_setprio(1);
#pragma unroll
        for (int df = 0; df < 4; ++df) {
            int row = df * 16 + lc;
            int key = (row & 7) << 4;
            s16x8 av0 = *(const s16x8*)(vlds + row * 128 + ((lq * 16) ^ key));
            s16x8 av1 = *(const s16x8*)(vlds + row * 128 + ((64 + lq * 16) ^ key));
            acc[df] = mfma_bf16(av0, ap0, acc[df]);
            acc[df] = mfma_bf16(av1, ap1, acc[df]);
        }
        __builtin_amdgcn_s_setprio(0);

        // ---- tail: KV(kt+1) landed; bias(kt+1) (newest 4) flies on ----
        __builtin_amdgcn_sched_barrier(0);
        asm volatile("s_waitcnt vmcnt(4) lgkmcnt(0)");
        __builtin_amdgcn_s_barrier();
        __builtin_amdgcn_sched_barrier(0);
    };

    for (int t = 0; t < 16; ++t) {
        iter(2 * t,     0);
        iter(2 * t + 1, 1);
    }
    asm volatile("s_waitcnt vmcnt(0)");   // retire dangling clamped prefetches

    // ---- epilogue: O[q=lc][d], hi/lo bf16 split for precise out-proj ----
    float inv = 1.f / lst;
    size_t rowb = ((size_t)(b * 2048 + q0 + lc)) * 512 + h * 64;
#pragma unroll
    for (int df = 0; df < 4; ++df) {
        u16x4 hi, lo;
#pragma unroll
        for (int r = 0; r < 4; ++r) {
            float o = acc[df][r] * inv;
            unsigned short hb = f2bf(o);
            hi[r] = hb;
            lo[r] = f2bf(o - bf2f(hb));
        }
        *(u16x4*)(ah + rowb + df * 16 + lq * 4) = hi;
        *(u16x4*)(al + rowb + df * 16 + lq * 4) = lo;
    }
}

// ---------------- K5: out = (Ah+Al)(Wh+Wl)^T * seq_mask  (3-term split) -----
__launch_bounds__(256)
__global__ void k_gemm_out(const unsigned short* __restrict__ Ah, const unsigned short* __restrict__ Al,
                           const unsigned short* __restrict__ Wh, const unsigned short* __restrict__ Wl,
                           const float* __restrict__ seq_mask, float* __restrict__ out) {
    __shared__ unsigned short ah_t[128 * 32], al_t[128 * 32], bh_t[128 * 32], bl_t[128 * 32];
    int tid = threadIdx.x, lane = tid & 63, wid = tid >> 6;
    int lc = lane & 15, lq = lane >> 4;
    int wr = wid >> 1, wc = wid & 1;
    int m0 = blockIdx.x * 128, n0 = blockIdx.y * 128;
    f32x4 acc[4][4];
#pragma unroll
    for (int i = 0; i < 4; ++i)
#pragma unroll
        for (int jn = 0; jn < 4; ++jn)
#pragma unroll
            for (int e = 0; e < 4; ++e) acc[i][jn][e] = 0.f;
    int wbase = wid * 64;
    for (int kt = 0; kt < 16; ++kt) {
        __syncthreads();
#pragma unroll
        for (int i = 0; i < 2; ++i) {
            int p = i * 256 + wbase + lane;
            int row = p >> 2, ls = (p & 3) ^ (row & 3);
            size_t asrc = (size_t)(m0 + row) * 512 + kt * 32 + ls * 8;
            size_t bsrc = (size_t)(n0 + row) * 512 + kt * 32 + ls * 8;
            int dst = (i * 256 + wbase) * 8;
            gl_lds16(Ah + asrc, ah_t + dst);
            gl_lds16(Al + asrc, al_t + dst);
            gl_lds16(Wh + bsrc, bh_t + dst);
            gl_lds16(Wl + bsrc, bl_t + dst);
        }
        __syncthreads();
        s16x8 fah[4], fal[4], fbh[4], fbl[4];
#pragma unroll
        for (int mf = 0; mf < 4; ++mf) {
            int row = wr * 64 + mf * 16 + lc;
            int off = row * 64 + ((lq * 16) ^ ((row & 3) << 4));
            fah[mf] = *(const s16x8*)((const char*)ah_t + off);
            fal[mf] = *(const s16x8*)((const char*)al_t + off);
        }
#pragma unroll
        for (int nf = 0; nf < 4; ++nf) {
            int row = wc * 64 + nf * 16 + lc;
            int off = row * 64 + ((lq * 16) ^ ((row & 3) << 4));
            fbh[nf] = *(const s16x8*)((const char*)bh_t + off);
            fbl[nf] = *(const s16x8*)((const char*)bl_t + off);
        }
#pragma unroll
        for (int mf = 0; mf < 4; ++mf)
#pragma unroll
            for (int nf = 0; nf < 4; ++nf) {
                acc[mf][nf] = mfma_bf16(fah[mf], fbh[nf], acc[mf][nf]);
                acc[mf][nf] = mfma_bf16(fah[mf], fbl[nf], acc[mf][nf]);
                acc[mf][nf] = mfma_bf16(fal[mf], fbh[nf], acc[mf][nf]);
            }
    }
#pragma unroll
    for (int mf = 0; mf < 4; ++mf)
#pragma unroll
        for (int nf = 0; nf < 4; ++nf)
#pragma unroll
            for (int r = 0; r < 4; ++r) {
                int grow = m0 + wr * 64 + mf * 16 + lq * 4 + r;
                int gcol = n0 + wc * 64 + nf * 16 + lc;
                out[(size_t)grow * 512 + gcol] = acc[mf][nf][r] * seq_mask[grow];
            }
}

// ---------------------------------------------------------------------------
extern "C" void kernel_launch(void* const* d_in, const int* in_sizes, int n_in,
                              void* d_out, int out_size, void* d_ws, size_t ws_size,
                              hipStream_t stream) {
    const float* x         = (const float*)d_in[0];
    const float* timev     = (const float*)d_in[1];
    const float* attn_bias = (const float*)d_in[2];
    const float* seq_mask  = (const float*)d_in[3];
    const float* gamma     = (const float*)d_in[4];
    const float* w_time    = (const float*)d_in[5];
    const float* b_time    = (const float*)d_in[6];
    const float* w_q       = (const float*)d_in[7];
    const float* w_kv      = (const float*)d_in[8];
    const float* w_out     = (const float*)d_in[9];
    float* out = (float*)d_out;

    char* ws = (char*)d_ws;
    size_t off = 0;
    auto alloc = [&](size_t bytes) {
        char* p = ws + off;
        off += (bytes + 255) & ~(size_t)255;
        return p;
    };
    float*          tc   = (float*)alloc(2048 * 4);
    unsigned short* wq   = (unsigned short*)alloc(262144 * 2);
    unsigned short* wkv  = (unsigned short*)alloc(524288 * 2);
    unsigned short* wo_h = (unsigned short*)alloc(262144 * 2);
    unsigned short* wo_l = (unsigned short*)alloc(262144 * 2);
    unsigned short* xbf  = (unsigned short*)alloc(2097152 * 2);
    unsigned short* xnbf = (unsigned short*)alloc(2097152 * 2);
    unsigned short* qb   = (unsigned short*)alloc(2097152 * 2);
    unsigned short* kb   = (unsigned short*)alloc(2097152 * 2);
    unsigned short* vtb  = (unsigned short*)alloc(2097152 * 2);
    unsigned short* ahh  = (unsigned short*)alloc(2097152 * 2);
    unsigned short* all_ = (unsigned short*)alloc(2097152 * 2);

    k_prep<<<4096, 256, 0, stream>>>(w_q, w_kv, w_out, wq, wkv, wo_h, wo_l);
    k_time<<<512, 256, 0, stream>>>(timev, w_time, b_time, tc);
    k_lnfilm<<<4096, 256, 0, stream>>>(x, gamma, seq_mask, tc, xbf, xnbf);
    k_gemm<0><<<dim3(32, 4), 256, 0, stream>>>(xnbf, wq, qb, nullptr);
    k_gemm<1><<<dim3(32, 8), 256, 0, stream>>>(xbf, wkv, kb, vtb);
    k_attn<<<512, 256, 0, stream>>>(qb, kb, vtb, attn_bias, seq_mask, ahh, all_);
    k_gemm_out<<<dim3(32, 4), 256, 0, stream>>>(ahh, all_, wo_h, wo_l, seq_mask, out);
}